// Round 14
// baseline (278.960 us; speedup 1.0000x reference)
//
#include <hip/hip_runtime.h>
#include <hip/hip_bf16.h>

#define EPSV 1e-5f

typedef float vf2 __attribute__((ext_vector_type(2)));
typedef _Float16 h4f __attribute__((ext_vector_type(4)));
typedef _Float16 h8f __attribute__((ext_vector_type(8)));

// Packed dual-FP32 FMA/MUL (VOP3P).
__device__ __forceinline__ vf2 pk_fma(vf2 a, vf2 b, vf2 c) {
  vf2 d;
  asm("v_pk_fma_f32 %0, %1, %2, %3" : "=v"(d) : "v"(a), "v"(b), "v"(c));
  return d;
}
__device__ __forceinline__ vf2 pk_mul(vf2 a, vf2 b) {
  vf2 d;
  asm("v_pk_mul_f32 %0, %1, %2" : "=v"(d) : "v"(a), "v"(b));
  return d;
}

// LDS-only barrier: does NOT drain vmcnt.
__device__ __forceinline__ void lds_barrier() {
  asm volatile("s_waitcnt lgkmcnt(0)" ::: "memory");
  __builtin_amdgcn_s_barrier();
}

// convert one h8f (8 fp16) into 4 vf2 with BN+relu
#define CVT4(dst, base, v, al, be)                               \
  dst[base + 0].x = fmaxf(al * (float)v[0] + be, 0.f);           \
  dst[base + 0].y = fmaxf(al * (float)v[1] + be, 0.f);           \
  dst[base + 1].x = fmaxf(al * (float)v[2] + be, 0.f);           \
  dst[base + 1].y = fmaxf(al * (float)v[3] + be, 0.f);           \
  dst[base + 2].x = fmaxf(al * (float)v[4] + be, 0.f);           \
  dst[base + 2].y = fmaxf(al * (float)v[5] + be, 0.f);           \
  dst[base + 3].x = fmaxf(al * (float)v[6] + be, 0.f);           \
  dst[base + 3].y = fmaxf(al * (float)v[7] + be, 0.f);

// workspace float offsets
#define WS_SUM0   0
#define WS_SSQ0   64
#define WS_SUM1   128
#define WS_SSQ1   192
#define WS_SUM2   256
#define WS_SSQ2   320
#define WS_AL0    384
#define WS_BE0    448
#define WS_ZBG    512
#define WS_T1BG   576      // 64*32 (fallback)
#define WS_AL1    2624
#define WS_BE1    2688
#define WS_T2BG   2752     // 64*16 (fallback)
#define WS_AL2    3776
#define WS_BE2    3840
#define WS_A2BG   3904
#define WS_OC     4928     // 9 used
#define WS_CU     4992     // 32 (fallback)
#define WS_CW     5120     // 5184: pre-repacked conv table
#define WS_WSUM   10304    // 9216: wsum[j][k*16+p]
#define WS_HSL    19584    // 16 slices * 2640 = 42240 (private histograms)
#define WS_T1     65536    // t1 fp16; layout [m][4 chunks][256 tid] h8 (16B)

#define CONV_LDS 5184
#define NHIST 2640

// slow repack — fallback only
__device__ __forceinline__ void stage_conv(float* sW, const float* __restrict__ conv_w,
                                           int nthr) {
  for (int i = threadIdx.x; i < 8000; i += nthr) {
    int k = i / 125, rem = i - k * 125;
    int cc = rem / 25, r2 = rem - cc * 25;
    int di = r2 / 5, dj = r2 - di * 5;
    if (di < 4 && dj < 4) sW[k * 81 + cc * 16 + di * 4 + dj] = conv_w[i];
  }
  for (int k = threadIdx.x; k < 64; k += nthr) sW[k * 81 + 80] = 0.f;
}

__device__ __forceinline__ void stage_conv_fast(float* sW, const float* __restrict__ cw) {
  const float4* src = (const float4*)cw;
  float4* dst = (float4*)sW;
  for (int i = threadIdx.x; i < CONV_LDS / 4; i += 256) dst[i] = src[i];
}

__device__ __forceinline__ int conv_idx(int di, int dj, int cc) {
  int idx = cc * 16 + di * 4 + dj;
  return ((di | dj) >= 0) ? idx : 80;
}

// ---------------------------------------------------------------------------
// Kernel P: blocks 0-7 repack conv_w; 8-43 wsum; 44-59 private histograms.
__global__ __launch_bounds__(256) void k_prep3(
    const int* __restrict__ x, const float* __restrict__ conv_w,
    const float* __restrict__ w_out, float* __restrict__ ws, int M) {
  __shared__ float h[NHIST];
  const int b = blockIdx.x;
  const int tid = threadIdx.x;
  if (b < 8) {
    float* cw = ws + WS_CW;
    const int gid = b * 256 + tid;
    for (int i = gid; i < 8000; i += 8 * 256) {
      int k = i / 125, rem = i - k * 125;
      int cc = rem / 25, r2 = rem - cc * 25;
      int di = r2 / 5, dj = r2 - di * 5;
      if (di < 4 && dj < 4) cw[k * 81 + cc * 16 + di * 4 + dj] = conv_w[i];
    }
    for (int k = gid; k < 64; k += 8 * 256) cw[k * 81 + 80] = 0.f;
  } else if (b < 44) {
    const int gid = (b - 8) * 256 + tid;
    if (gid < 9216) {
      int j = gid / 1024, kp = gid - j * 1024;
      int k = kp >> 4, p = kp & 15;
      float s = 0.f;
#pragma unroll
      for (int yy = 4; yy < 11; ++yy)
        s += w_out[j * 11264 + k * 176 + yy * 16 + p];
      ws[WS_WSUM + gid] = s;
    }
  } else {
    const int slice = b - 44;
    for (int i = tid; i < NHIST; i += 256) h[i] = 0.f;
    __syncthreads();
    for (int m = slice * 256 + tid; m < M; m += 16 * 256) {
      int v[5];
      const int2* xp = (const int2*)(x + m * 10);
#pragma unroll
      for (int cc = 0; cc < 5; ++cc) {
        int2 t = xp[cc];
        v[cc] = (t.x << 2) | t.y;
      }
#pragma unroll
      for (int cc = 0; cc < 5; ++cc) atomicAdd(&h[cc * 16 + v[cc]], 1.f);
      int pr = 0;
#pragma unroll
      for (int a = 0; a < 5; ++a)
#pragma unroll
        for (int bb = a + 1; bb < 5; ++bb) {
          atomicAdd(&h[80 + pr * 256 + v[a] * 16 + v[bb]], 1.f);
          ++pr;
        }
    }
    __syncthreads();
    for (int i = tid; i < NHIST; i += 256)
      ws[WS_HSL + slice * NHIST + i] = h[i];
  }
}

// ---------------------------------------------------------------------------
// Kernel S: BN0 stats from private histogram slices. One block per channel k.
__global__ __launch_bounds__(256) void k_stats0h(
    const float* __restrict__ conv_b, float* __restrict__ ws, int M) {
  __shared__ float sWk[81];
  __shared__ float sH[NHIST];
  __shared__ float sRed[8];
  const int tid = threadIdx.x;
  const int k = blockIdx.x;
  if (tid < 81) sWk[tid] = ws[WS_CW + k * 81 + tid];
  for (int i = tid; i < NHIST; i += 256) {
    float s = 0.f;
#pragma unroll
    for (int sl = 0; sl < 16; ++sl) s += ws[WS_HSL + sl * NHIST + i];
    sH[i] = s;
  }
  __syncthreads();
  const float cb = conv_b[k];
  float L = 0.f, Q = 0.f, P = 0.f;
  for (int it = tid; it < 1280; it += 256) {
    int pos = it / 80, rem = it - pos * 80;
    int cc = rem >> 4, v = rem & 15;
    int y = pos >> 2, xx = pos & 3;
    float w = sWk[conv_idx((v >> 2) - y, (v & 3) - xx, cc)];
    float n = sH[cc * 16 + v];
    L += n * w;
    Q += n * w * w;
  }
  if (tid < 160) {
    int pos = tid / 10, pr = tid - pos * 10;
    int y = pos >> 2, xx = pos & 3;
    int a, b;
    if (pr < 4)      { a = 0; b = pr + 1; }
    else if (pr < 7) { a = 1; b = pr - 2; }
    else if (pr < 9) { a = 2; b = pr - 4; }
    else             { a = 3; b = 4; }
    const float* Hp = sH + 80 + pr * 256;
    for (int v1 = 0; v1 < 16; ++v1) {
      float w1 = sWk[conv_idx((v1 >> 2) - y, (v1 & 3) - xx, a)];
      float acc = 0.f;
#pragma unroll
      for (int v2 = 0; v2 < 16; ++v2) {
        float w2 = sWk[conv_idx((v2 >> 2) - y, (v2 & 3) - xx, b)];
        acc += Hp[v1 * 16 + v2] * w2;
      }
      P += w1 * acc;
    }
  }
  float A = L, B = Q + 2.f * cb * L + 2.f * P;
  A += __shfl_xor(A, 1);  B += __shfl_xor(B, 1);
  A += __shfl_xor(A, 2);  B += __shfl_xor(B, 2);
  A += __shfl_xor(A, 4);  B += __shfl_xor(B, 4);
  A += __shfl_xor(A, 8);  B += __shfl_xor(B, 8);
  A += __shfl_xor(A, 16); B += __shfl_xor(B, 16);
  A += __shfl_xor(A, 32); B += __shfl_xor(B, 32);
  const int lane = tid & 63, wv = tid >> 6;
  if (lane == 0) { sRed[wv * 2] = A; sRed[wv * 2 + 1] = B; }
  __syncthreads();
  if (tid == 0) {
    float At = sRed[0] + sRed[2] + sRed[4] + sRed[6];
    float Bt = sRed[1] + sRed[3] + sRed[5] + sRed[7];
    const float a16 = 16.f * (float)M;
    ws[WS_SUM0 + k] = At + a16 * cb;
    ws[WS_SSQ0 + k] = Bt + a16 * cb * cb;
    ws[WS_SUM1 + k] = 0.f;
    ws[WS_SSQ1 + k] = 0.f;
    ws[WS_SUM2 + k] = 0.f;
    ws[WS_SSQ2 + k] = 0.f;
  }
}

// ---------------------------------------------------------------------------
// Kernel 3 (round-8 codegen, grid 256): DUAL-m conv -> r1 -> h1(pk_fma,
// LDS fp32 weights) -> t1 (fp16 h8 stores); BN0 folded in; sched_barriers
// kept (register-pressure limiters). 8 pairs/block amortizes conv staging.
__global__ __launch_bounds__(256) void k_t1(
    const int* __restrict__ x, const float* __restrict__ conv_b,
    const float* __restrict__ g0, const float* __restrict__ b0,
    const float* __restrict__ w_rank, const float* __restrict__ b_rank,
    const float* __restrict__ w_h1, const float* __restrict__ b_h1,
    float* __restrict__ ws, float* __restrict__ t1, int M) {
  __shared__ float sW[CONV_LDS];
  __shared__ float sWh1[1024];
  __shared__ float sCU[32];
  stage_conv_fast(sW, ws + WS_CW);
  {
    const float4* src = (const float4*)w_h1;
    float4* dst = (float4*)sWh1;
    if (threadIdx.x < 256) dst[threadIdx.x] = src[threadIdx.x];
  }
  if (threadIdx.x < 32) {
    float cuv = 0.f;
    for (int s2 = 4; s2 < 10; ++s2) cuv += w_rank[threadIdx.x * 10 + s2];
    sCU[threadIdx.x] = cuv;
  }
  __syncthreads();
  const int tid = threadIdx.x;
  const int y = tid & 3, k = tid >> 2;
  const float cb = conv_b[k];
  const float n0 = 110.f * (float)M;
  const float S0  = ws[WS_SUM0 + k] + 94.f * (float)M * cb;
  const float SS0 = ws[WS_SSQ0 + k] + 94.f * (float)M * cb * cb;
  const float mu0 = S0 / n0;
  const float var0 = SS0 / n0 - mu0 * mu0;
  const float al = rsqrtf(var0 + EPSV) * g0[k];
  const float be = b0[k] - mu0 * al;
  const float zbg = fmaxf(cb * al + be, 0.f);
  const float* Wk = &sW[k * 81];
  const vf2* wrp = (const vf2*)w_rank;
  const vf2* w1p = (const vf2*)sWh1;
  h8f* t1h8 = (h8f*)t1;
  float sAcc = 0.f, ssAcc = 0.f;
  const int NP = (M + 1) >> 1;
  for (int mp = blockIdx.x; mp < NP; mp += gridDim.x) {
    const int mA = mp * 2, mB = mA + 1;
    const bool hasB = (mB < M);
    const int mBs = hasB ? mB : mA;
    int rA[5], cA[5], rB[5], cBx[5];
    const int2* xpA = (const int2*)(x + mA * 10);
    const int2* xpB = (const int2*)(x + mBs * 10);
#pragma unroll
    for (int cc = 0; cc < 5; ++cc) {
      int2 tA = xpA[cc]; rA[cc] = tA.x; cA[cc] = tA.y;
      int2 tB = xpB[cc]; rB[cc] = tB.x; cBx[cc] = tB.y;
    }
    float a0A[4], a0B[4];
#pragma unroll
    for (int xx = 0; xx < 4; ++xx) {
      float vA = cb, vB = cb;
#pragma unroll
      for (int cc = 0; cc < 5; ++cc) {
        vA += Wk[conv_idx(rA[cc] - y, cA[cc] - xx, cc)];
        vB += Wk[conv_idx(rB[cc] - y, cBx[cc] - xx, cc)];
      }
      a0A[xx] = fmaxf(al * vA + be, 0.f);
      a0B[xx] = fmaxf(al * vB + be, 0.f);
    }
    vf2 aAp[2], aBp[2];
    aAp[0].x = a0A[0]; aAp[0].y = a0A[1];
    aAp[1].x = a0A[2]; aAp[1].y = a0A[3];
    aBp[0].x = a0B[0]; aBp[0].y = a0B[1];
    aBp[1].x = a0B[2]; aBp[1].y = a0B[3];
    __builtin_amdgcn_sched_barrier(0);
    vf2 r1A[16], r1B[16];
#pragma unroll
    for (int o2 = 0; o2 < 16; ++o2) {
      const int oa = 2 * o2, ob = oa + 1;
      vf2 w0 = wrp[oa * 5], w1 = wrp[oa * 5 + 1];
      vf2 w2 = wrp[ob * 5], w3 = wrp[ob * 5 + 1];
      const float basea = b_rank[oa] + zbg * sCU[oa];
      const float baseb = b_rank[ob] + zbg * sCU[ob];
      vf2 accAa = pk_mul(aAp[0], w0); accAa = pk_fma(aAp[1], w1, accAa);
      vf2 accAb = pk_mul(aAp[0], w2); accAb = pk_fma(aAp[1], w3, accAb);
      vf2 accBa = pk_mul(aBp[0], w0); accBa = pk_fma(aBp[1], w1, accBa);
      vf2 accBb = pk_mul(aBp[0], w2); accBb = pk_fma(aBp[1], w3, accBb);
      vf2 ra, rb;
      ra.x = fmaxf(basea + accAa.x + accAa.y, 0.f);
      ra.y = fmaxf(baseb + accAb.x + accAb.y, 0.f);
      rb.x = fmaxf(basea + accBa.x + accBa.y, 0.f);
      rb.y = fmaxf(baseb + accBb.x + accBb.y, 0.f);
      r1A[o2] = ra;
      r1B[o2] = rb;
    }
    __builtin_amdgcn_sched_barrier(0);
    float sBm = 0.f, ssBm = 0.f;
#pragma unroll
    for (int ch = 0; ch < 4; ++ch) {
      float accA[8], accB[8];
#pragma unroll
      for (int u = 0; u < 8; ++u) {
        const int o = ch * 8 + u;
        vf2 a2A = {0.f, 0.f}, a2B = {0.f, 0.f};
#pragma unroll
        for (int i = 0; i < 16; ++i) {
          vf2 w = w1p[o * 16 + i];
          a2A = pk_fma(r1A[i], w, a2A);
          a2B = pk_fma(r1B[i], w, a2B);
        }
        const float bb = b_h1[o];
        float aA = bb + a2A.x + a2A.y;
        float aB = bb + a2B.x + a2B.y;
        accA[u] = aA; accB[u] = aB;
        sAcc += aA; ssAcc += aA * aA;
        sBm += aB;  ssBm += aB * aB;
      }
      h8f stA;
#pragma unroll
      for (int u = 0; u < 8; ++u) stA[u] = (_Float16)accA[u];
      t1h8[((size_t)mA * 4 + ch) * 256 + tid] = stA;
      if (hasB) {
        h8f stB;
#pragma unroll
        for (int u = 0; u < 8; ++u) stB[u] = (_Float16)accB[u];
        t1h8[((size_t)mB * 4 + ch) * 256 + tid] = stB;
      }
      __builtin_amdgcn_sched_barrier(0);
    }
    if (hasB) { sAcc += sBm; ssAcc += ssBm; }
  }
  sAcc  += __shfl_xor(sAcc, 1);  sAcc  += __shfl_xor(sAcc, 2);
  ssAcc += __shfl_xor(ssAcc, 1); ssAcc += __shfl_xor(ssAcc, 2);
  if (y == 0) {
    atomicAdd(&ws[WS_SUM1 + k], sAcc);
    atomicAdd(&ws[WS_SSQ1 + k], ssAcc);
  }
}

// ---------------------------------------------------------------------------
// Kernel 5: BN1 finalize folded in; grid 512, 4 pairs/block, 2-deep prefetch.
__global__ __launch_bounds__(256) void k_t2(
    const float* __restrict__ conv_b, const float* __restrict__ g0,
    const float* __restrict__ b0, const float* __restrict__ w_rank,
    const float* __restrict__ b_rank, const float* __restrict__ w_h1,
    const float* __restrict__ b_h1, const float* __restrict__ g1,
    const float* __restrict__ b1, const float* __restrict__ w_h2,
    const float* __restrict__ b_h2, float* __restrict__ ws,
    float* __restrict__ t1, int M) {
  __shared__ float sS[32];
  __shared__ float sWh1[1024];
  const int tid = threadIdx.x;
  for (int i = tid; i < 1024; i += 256) sWh1[i] = w_h1[i];
  if (tid < 32) {
    float s = 0.f;
    for (int s2 = 0; s2 < 10; ++s2) s += w_rank[tid * 10 + s2];
    sS[tid] = s;
  }
  __syncthreads();
  const int y = tid & 3, k = tid >> 2;
  const float fM = (float)M;
  const float cb = conv_b[k];
  const float n0 = 110.f * fM;
  const float S0  = ws[WS_SUM0 + k] + 94.f * fM * cb;
  const float SS0 = ws[WS_SSQ0 + k] + 94.f * fM * cb * cb;
  const float mu0 = S0 / n0;
  const float al0 = rsqrtf(SS0 / n0 - mu0 * mu0 + EPSV) * g0[k];
  const float be0 = b0[k] - mu0 * al0;
  const float zbg = fmaxf(cb * al0 + be0, 0.f);
  float r1bg[32];
#pragma unroll
  for (int o = 0; o < 32; ++o) r1bg[o] = fmaxf(zbg * sS[o] + b_rank[o], 0.f);
  float sb = 0.f, ssb = 0.f;
#pragma unroll
  for (int u = 0; u < 8; ++u) {
    const int o = y * 8 + u;
    float a = b_h1[o];
#pragma unroll
    for (int i = 0; i < 32; ++i) a += r1bg[i] * sWh1[o * 32 + i];
    sb += a;
    ssb += a * a;
  }
  sb  += __shfl_xor(sb, 1);  sb  += __shfl_xor(sb, 2);
  ssb += __shfl_xor(ssb, 1); ssb += __shfl_xor(ssb, 2);
  const float n1 = fM * 11.f * 32.f;
  const float S1  = ws[WS_SUM1 + k] + 7.f * fM * sb;
  const float SS1 = ws[WS_SSQ1 + k] + 7.f * fM * ssb;
  const float mu1 = S1 / n1;
  const float al1 = rsqrtf(SS1 / n1 - mu1 * mu1 + EPSV) * g1[k];
  const float be1 = b1[k] - mu1 * al1;
  // main loop with prefetch pipeline
  const vf2* w2p = (const vf2*)w_h2;
  h8f* t1h8 = (h8f*)t1;
  float sAcc = 0.f, ssAcc = 0.f;
  const int NP = (M + 1) >> 1;
  const int G = gridDim.x;
  int mp = blockIdx.x;
  h8f cA0, cA1, cA2, cA3, cB0, cB1, cB2, cB3;
  h8f nA0, nA1, nA2, nA3, nB0, nB1, nB2, nB3;
  if (mp < NP) {
    const int mA = mp * 2;
    const int mBs = (mA + 1 < M) ? mA + 1 : mA;
    cA0 = t1h8[((size_t)mA * 4 + 0) * 256 + tid];
    cA1 = t1h8[((size_t)mA * 4 + 1) * 256 + tid];
    cA2 = t1h8[((size_t)mA * 4 + 2) * 256 + tid];
    cA3 = t1h8[((size_t)mA * 4 + 3) * 256 + tid];
    cB0 = t1h8[((size_t)mBs * 4 + 0) * 256 + tid];
    cB1 = t1h8[((size_t)mBs * 4 + 1) * 256 + tid];
    cB2 = t1h8[((size_t)mBs * 4 + 2) * 256 + tid];
    cB3 = t1h8[((size_t)mBs * 4 + 3) * 256 + tid];
  }
  while (mp < NP) {
    const int mA = mp * 2, mB = mA + 1;
    const bool hasB = (mB < M);
    const int mpn = mp + G;
    if (mpn < NP) {
      const int mAn = mpn * 2;
      const int mBn = (mAn + 1 < M) ? mAn + 1 : mAn;
      nA0 = t1h8[((size_t)mAn * 4 + 0) * 256 + tid];
      nA1 = t1h8[((size_t)mAn * 4 + 1) * 256 + tid];
      nA2 = t1h8[((size_t)mAn * 4 + 2) * 256 + tid];
      nA3 = t1h8[((size_t)mAn * 4 + 3) * 256 + tid];
      nB0 = t1h8[((size_t)mBn * 4 + 0) * 256 + tid];
      nB1 = t1h8[((size_t)mBn * 4 + 1) * 256 + tid];
      nB2 = t1h8[((size_t)mBn * 4 + 2) * 256 + tid];
      nB3 = t1h8[((size_t)mBn * 4 + 3) * 256 + tid];
    }
    vf2 a1A[16], a1B[16];
    CVT4(a1A, 0,  cA0, al1, be1);
    CVT4(a1A, 4,  cA1, al1, be1);
    CVT4(a1A, 8,  cA2, al1, be1);
    CVT4(a1A, 12, cA3, al1, be1);
    CVT4(a1B, 0,  cB0, al1, be1);
    CVT4(a1B, 4,  cB1, al1, be1);
    CVT4(a1B, 8,  cB2, al1, be1);
    CVT4(a1B, 12, cB3, al1, be1);
    float sBm = 0.f, ssBm = 0.f;
#pragma unroll
    for (int pv2 = 0; pv2 < 2; ++pv2) {
      float accA[8], accB[8];
#pragma unroll
      for (int u = 0; u < 8; ++u) {
        const int p = pv2 * 8 + u;
        vf2 a2A = {0.f, 0.f}, a2B = {0.f, 0.f};
#pragma unroll
        for (int i = 0; i < 16; ++i) {
          vf2 w = w2p[p * 16 + i];
          a2A = pk_fma(a1A[i], w, a2A);
          a2B = pk_fma(a1B[i], w, a2B);
        }
        const float bb = b_h2[p];
        float aA = bb + a2A.x + a2A.y;
        float aB = bb + a2B.x + a2B.y;
        accA[u] = aA; accB[u] = aB;
        sAcc += aA; ssAcc += aA * aA;
        sBm += aB;  ssBm += aB * aB;
      }
      h8f stA;
#pragma unroll
      for (int u = 0; u < 8; ++u) stA[u] = (_Float16)accA[u];
      t1h8[((size_t)mA * 4 + pv2) * 256 + tid] = stA;
      if (hasB) {
        h8f stB;
#pragma unroll
        for (int u = 0; u < 8; ++u) stB[u] = (_Float16)accB[u];
        t1h8[((size_t)mB * 4 + pv2) * 256 + tid] = stB;
      }
    }
    if (hasB) { sAcc += sBm; ssAcc += ssBm; }
    mp = mpn;
    if (mp < NP) {
      cA0 = nA0; cA1 = nA1; cA2 = nA2; cA3 = nA3;
      cB0 = nB0; cB1 = nB1; cB2 = nB2; cB3 = nB3;
    }
  }
  sAcc  += __shfl_xor(sAcc, 1);  sAcc  += __shfl_xor(sAcc, 2);
  ssAcc += __shfl_xor(ssAcc, 1); ssAcc += __shfl_xor(ssAcc, 2);
  if (y == 0) {
    atomicAdd(&ws[WS_SUM2 + k], sAcc);
    atomicAdd(&ws[WS_SSQ2 + k], ssAcc);
  }
}

// ---------------------------------------------------------------------------
// Kernel 6: one block; recomputes bg chain; finalizes BN2; OC via wsum.
__global__ __launch_bounds__(256) void k_fin2p(
    const float* __restrict__ conv_b, const float* __restrict__ g0,
    const float* __restrict__ b0, const float* __restrict__ w_rank,
    const float* __restrict__ b_rank, const float* __restrict__ w_h1,
    const float* __restrict__ b_h1, const float* __restrict__ g1,
    const float* __restrict__ b1, const float* __restrict__ w_h2,
    const float* __restrict__ b_h2, const float* __restrict__ g2,
    const float* __restrict__ b2, const float* __restrict__ b_out,
    float* __restrict__ ws, int M) {
  __shared__ float sS[32];
  __shared__ float sWh1[1024];
  __shared__ float sWh2[512];
  __shared__ float sWs[9216];
  __shared__ float sA2[1024];
  __shared__ float red[576];
  const int tid = threadIdx.x;
  for (int i = tid; i < 1024; i += 256) sWh1[i] = w_h1[i];
  for (int i = tid; i < 512; i += 256) sWh2[i] = w_h2[i];
  for (int i = tid; i < 9216; i += 256) sWs[i] = ws[WS_WSUM + i];
  if (tid < 32) {
    float s = 0.f;
    for (int s2 = 0; s2 < 10; ++s2) s += w_rank[tid * 10 + s2];
    sS[tid] = s;
  }
  __syncthreads();
  const int k = tid >> 2, q = tid & 3;
  const float fM = (float)M;
  const float cb = conv_b[k];
  const float n0 = 110.f * fM;
  const float S0  = ws[WS_SUM0 + k] + 94.f * fM * cb;
  const float SS0 = ws[WS_SSQ0 + k] + 94.f * fM * cb * cb;
  const float mu0 = S0 / n0;
  const float al0 = rsqrtf(SS0 / n0 - mu0 * mu0 + EPSV) * g0[k];
  const float be0 = b0[k] - mu0 * al0;
  const float zbg = fmaxf(cb * al0 + be0, 0.f);
  float r1bg[32];
#pragma unroll
  for (int o = 0; o < 32; ++o) r1bg[o] = fmaxf(zbg * sS[o] + b_rank[o], 0.f);
  float t1bg[8];
  float sb = 0.f, ssb = 0.f;
#pragma unroll
  for (int u = 0; u < 8; ++u) {
    const int o = q * 8 + u;
    float a = b_h1[o];
#pragma unroll
    for (int i = 0; i < 32; ++i) a += r1bg[i] * sWh1[o * 32 + i];
    t1bg[u] = a;
    sb += a;
    ssb += a * a;
  }
  sb  += __shfl_xor(sb, 1);  sb  += __shfl_xor(sb, 2);
  ssb += __shfl_xor(ssb, 1); ssb += __shfl_xor(ssb, 2);
  const float n1 = fM * 11.f * 32.f;
  const float S1  = ws[WS_SUM1 + k] + 7.f * fM * sb;
  const float SS1 = ws[WS_SSQ1 + k] + 7.f * fM * ssb;
  const float mu1 = S1 / n1;
  const float al1 = rsqrtf(SS1 / n1 - mu1 * mu1 + EPSV) * g1[k];
  const float be1 = b1[k] - mu1 * al1;
  float a1bg[8];
#pragma unroll
  for (int u = 0; u < 8; ++u) a1bg[u] = fmaxf(al1 * t1bg[u] + be1, 0.f);
  float pt[16];
#pragma unroll
  for (int p = 0; p < 16; ++p) {
    float a = 0.f;
#pragma unroll
    for (int u = 0; u < 8; ++u) a += a1bg[u] * sWh2[p * 32 + q * 8 + u];
    pt[p] = a;
  }
#pragma unroll
  for (int p = 0; p < 16; ++p) {
    pt[p] += __shfl_xor(pt[p], 1);
    pt[p] += __shfl_xor(pt[p], 2);
  }
  float sb2 = 0.f, ssb2 = 0.f;
#pragma unroll
  for (int p = 0; p < 16; ++p) {
    float v = pt[p] + b_h2[p];
    pt[p] = v;
    sb2 += v;
    ssb2 += v * v;
  }
  const float n2 = fM * 11.f * 16.f;
  const float S2  = ws[WS_SUM2 + k] + 7.f * fM * sb2;
  const float SS2 = ws[WS_SSQ2 + k] + 7.f * fM * ssb2;
  const float mu2 = S2 / n2;
  const float al2 = rsqrtf(SS2 / n2 - mu2 * mu2 + EPSV) * g2[k];
  const float be2 = b2[k] - mu2 * al2;
  if (q == 0) {
    ws[WS_AL2 + k] = al2;
    ws[WS_BE2 + k] = be2;
  }
#pragma unroll
  for (int v2 = 0; v2 < 4; ++v2) {
    const int p = q * 4 + v2;
    sA2[k * 16 + p] = fmaxf(al2 * pt[p] + be2, 0.f);
  }
  __syncthreads();
  for (int u = tid; u < 576; u += 256) {
    const int kk = u / 9, j = u - kk * 9;
    float acc = 0.f;
#pragma unroll
    for (int p = 0; p < 16; ++p)
      acc += sA2[kk * 16 + p] * sWs[j * 1024 + kk * 16 + p];
    red[u] = acc;
  }
  __syncthreads();
  if (tid < 9) {
    float acc = b_out[tid];
    for (int t = 0; t < 64; ++t) acc += red[t * 9 + tid];
    ws[WS_OC + tid] = acc;
  }
}

// ---------------------------------------------------------------------------
// Kernel 7: grid 512, prefetch pipeline; 16B t2 loads; LDS-only barriers.
__global__ __launch_bounds__(256) void k_out(
    const float* __restrict__ w_out, const float* __restrict__ ws,
    const float* __restrict__ t1, float* __restrict__ out, int M) {
  __shared__ float sOC[9];
  __shared__ float sP[256][19];
  __shared__ float sR2[18 * 8];
  if (threadIdx.x < 9) sOC[threadIdx.x] = ws[WS_OC + threadIdx.x];
  const int tid = threadIdx.x;
  const int y = tid & 3, k = tid >> 2;
  const float al2 = ws[WS_AL2 + k], be2 = ws[WS_BE2 + k];
  const float4* wo = (const float4*)(w_out + k * 176 + y * 16);
  const h8f* t2h8 = (const h8f*)t1;
  const int NP = (M + 1) >> 1;
  const int G = gridDim.x;
  int mp = blockIdx.x;
  h8f cA0, cA1, cB0, cB1, nA0, nA1, nB0, nB1;
  if (mp < NP) {
    const int mA = mp * 2;
    const int mBs = (mA + 1 < M) ? mA + 1 : mA;
    cA0 = t2h8[((size_t)mA * 4 + 0) * 256 + tid];
    cA1 = t2h8[((size_t)mA * 4 + 1) * 256 + tid];
    cB0 = t2h8[((size_t)mBs * 4 + 0) * 256 + tid];
    cB1 = t2h8[((size_t)mBs * 4 + 1) * 256 + tid];
  }
  bool first = true;
  while (mp < NP) {
    const int mA = mp * 2, mB = mA + 1;
    const bool hasB = (mB < M);
    const int mpn = mp + G;
    if (mpn < NP) {
      const int mAn = mpn * 2;
      const int mBn = (mAn + 1 < M) ? mAn + 1 : mAn;
      nA0 = t2h8[((size_t)mAn * 4 + 0) * 256 + tid];
      nA1 = t2h8[((size_t)mAn * 4 + 1) * 256 + tid];
      nB0 = t2h8[((size_t)mBn * 4 + 0) * 256 + tid];
      nB1 = t2h8[((size_t)mBn * 4 + 1) * 256 + tid];
    }
    vf2 a2A[8], a2B[8];
    CVT4(a2A, 0, cA0, al2, be2);
    CVT4(a2A, 4, cA1, al2, be2);
    CVT4(a2B, 0, cB0, al2, be2);
    CVT4(a2B, 4, cB1, al2, be2);
    if (!first) lds_barrier();
    first = false;
#pragma unroll
    for (int j = 0; j < 9; ++j) {
      float4 w0 = wo[j * 2816 + 0], w1 = wo[j * 2816 + 1];
      float4 w2 = wo[j * 2816 + 2], w3 = wo[j * 2816 + 3];
      vf2 aA = {0.f, 0.f}, aB = {0.f, 0.f};
      vf2 t;
      t.x = w0.x; t.y = w0.y; aA = pk_fma(a2A[0], t, aA); aB = pk_fma(a2B[0], t, aB);
      t.x = w0.z; t.y = w0.w; aA = pk_fma(a2A[1], t, aA); aB = pk_fma(a2B[1], t, aB);
      t.x = w1.x; t.y = w1.y; aA = pk_fma(a2A[2], t, aA); aB = pk_fma(a2B[2], t, aB);
      t.x = w1.z; t.y = w1.w; aA = pk_fma(a2A[3], t, aA); aB = pk_fma(a2B[3], t, aB);
      t.x = w2.x; t.y = w2.y; aA = pk_fma(a2A[4], t, aA); aB = pk_fma(a2B[4], t, aB);
      t.x = w2.z; t.y = w2.w; aA = pk_fma(a2A[5], t, aA); aB = pk_fma(a2B[5], t, aB);
      t.x = w3.x; t.y = w3.y; aA = pk_fma(a2A[6], t, aA); aB = pk_fma(a2B[6], t, aB);
      t.x = w3.z; t.y = w3.w; aA = pk_fma(a2A[7], t, aA); aB = pk_fma(a2B[7], t, aB);
      sP[tid][j] = aA.x + aA.y;
      sP[tid][9 + j] = aB.x + aB.y;
    }
    lds_barrier();
    if (tid < 144) {
      const int slot = tid / 8, part = tid & 7;
      float s = 0.f;
#pragma unroll 8
      for (int t = 0; t < 32; ++t) s += sP[part + t * 8][slot];
      sR2[slot * 8 + part] = s;
    }
    lds_barrier();
    if (tid < 18) {
      float s = 0.f;
#pragma unroll
      for (int p8 = 0; p8 < 8; ++p8) s += sR2[tid * 8 + p8];
      if (tid < 9) out[mA * 9 + tid] = sOC[tid] + s;
      else if (hasB) out[mB * 9 + (tid - 9)] = sOC[tid - 9] + s;
    }
    mp = mpn;
    if (mp < NP) {
      cA0 = nA0; cA1 = nA1; cB0 = nB0; cB1 = nB1;
    }
  }
}

// ===========================================================================
// FALLBACK PATH (ws too small): self-contained recompute kernels.
// ===========================================================================
__global__ __launch_bounds__(64) void k_fin0(
    const float* __restrict__ conv_b, const float* __restrict__ g0,
    const float* __restrict__ b0, const float* __restrict__ w_rank,
    const float* __restrict__ b_rank, const float* __restrict__ w_h1,
    const float* __restrict__ b_h1, float* __restrict__ ws, int M) {
  __shared__ float sS[32];
  const int t = threadIdx.x;
  if (t < 32) {
    float su = 0.f;
    for (int s2 = 0; s2 < 10; ++s2) su += w_rank[t * 10 + s2];
    sS[t] = su;
    float cu = 0.f;
    for (int s2 = 4; s2 < 10; ++s2) cu += w_rank[t * 10 + s2];
    ws[WS_CU + t] = cu;
  }
  __syncthreads();
  const int k = t;
  const float n0 = 110.f * (float)M;
  const float cb = conv_b[k];
  const float S  = ws[WS_SUM0 + k] + 94.f * (float)M * cb;
  const float SS = ws[WS_SSQ0 + k] + 94.f * (float)M * cb * cb;
  const float mu = S / n0;
  const float var = SS / n0 - mu * mu;
  const float rstd = rsqrtf(var + EPSV);
  const float al = rstd * g0[k];
  const float be = b0[k] - mu * al;
  ws[WS_AL0 + k] = al;
  ws[WS_BE0 + k] = be;
  const float zbg = fmaxf(cb * al + be, 0.f);
  ws[WS_ZBG + k] = zbg;
  float r1bg[32];
#pragma unroll
  for (int o = 0; o < 32; ++o) r1bg[o] = fmaxf(zbg * sS[o] + b_rank[o], 0.f);
  float sb = 0.f, ssb = 0.f;
  for (int o = 0; o < 32; ++o) {
    float acc = b_h1[o];
#pragma unroll
    for (int i = 0; i < 32; ++i) acc += r1bg[i] * w_h1[o * 32 + i];
    ws[WS_T1BG + k * 32 + o] = acc;
    sb += acc;
    ssb += acc * acc;
  }
  ws[WS_SUM1 + k] = 7.f * (float)M * sb;
  ws[WS_SSQ1 + k] = 7.f * (float)M * ssb;
}

__global__ __launch_bounds__(64) void k_fin1(
    const float* __restrict__ g1, const float* __restrict__ b1,
    const float* __restrict__ w_h2, const float* __restrict__ b_h2,
    float* __restrict__ ws, int M) {
  const int k = threadIdx.x;
  const float n1 = (float)M * 11.f * 32.f;
  const float S = ws[WS_SUM1 + k], SS = ws[WS_SSQ1 + k];
  const float mu = S / n1;
  const float var = SS / n1 - mu * mu;
  const float rstd = rsqrtf(var + EPSV);
  const float al = rstd * g1[k];
  const float be = b1[k] - mu * al;
  ws[WS_AL1 + k] = al;
  ws[WS_BE1 + k] = be;
  float a1bg[32];
#pragma unroll
  for (int o = 0; o < 32; ++o)
    a1bg[o] = fmaxf(al * ws[WS_T1BG + k * 32 + o] + be, 0.f);
  float sb = 0.f, ssb = 0.f;
  for (int p = 0; p < 16; ++p) {
    float acc = b_h2[p];
#pragma unroll
    for (int o = 0; o < 32; ++o) acc += a1bg[o] * w_h2[p * 32 + o];
    ws[WS_T2BG + k * 16 + p] = acc;
    sb += acc;
    ssb += acc * acc;
  }
  ws[WS_SUM2 + k] = 7.f * (float)M * sb;
  ws[WS_SSQ2 + k] = 7.f * (float)M * ssb;
}

__global__ __launch_bounds__(256) void k_stats0(
    const int* __restrict__ x, const float* __restrict__ conv_w,
    const float* __restrict__ conv_b, float* __restrict__ ws, int M) {
  __shared__ float sW[CONV_LDS];
  stage_conv(sW, conv_w, 256);
  __syncthreads();
  const int tid = threadIdx.x;
  const int mg = tid & 3;
  const int k  = tid >> 2;
  const float cb = conv_b[k];
  const float* Wk = &sW[k * 81];
  float s = 0.f, ss = 0.f;
  for (int m = blockIdx.x * 4 + mg; m < M; m += gridDim.x * 4) {
    int r[5], c[5];
    const int2* xp = (const int2*)(x + m * 10);
#pragma unroll
    for (int cc = 0; cc < 5; ++cc) { int2 t = xp[cc]; r[cc] = t.x; c[cc] = t.y; }
#pragma unroll
    for (int y = 0; y < 4; ++y) {
#pragma unroll
      for (int xx = 0; xx < 4; ++xx) {
        float v = cb;
#pragma unroll
        for (int cc = 0; cc < 5; ++cc)
          v += Wk[conv_idx(r[cc] - y, c[cc] - xx, cc)];
        s += v;
        ss += v * v;
      }
      __builtin_amdgcn_sched_barrier(0);
    }
  }
  s  += __shfl_xor(s, 1);  s  += __shfl_xor(s, 2);
  ss += __shfl_xor(ss, 1); ss += __shfl_xor(ss, 2);
  if (mg == 0) {
    atomicAdd(&ws[WS_SUM0 + k], s);
    atomicAdd(&ws[WS_SSQ0 + k], ss);
  }
}

__global__ __launch_bounds__(256) void k_stats1(
    const int* __restrict__ x, const float* __restrict__ conv_w,
    const float* __restrict__ conv_b, const float* __restrict__ w_rank,
    const float* __restrict__ b_rank, const float* __restrict__ w_h1,
    const float* __restrict__ b_h1, float* __restrict__ ws, int M) {
  __shared__ float sW[CONV_LDS];
  stage_conv(sW, conv_w, 256);
  __syncthreads();
  const int tid = threadIdx.x;
  const int y = tid & 3, k = tid >> 2;
  const float cb = conv_b[k];
  const float al = ws[WS_AL0 + k], be = ws[WS_BE0 + k], zbg = ws[WS_ZBG + k];
  const float* Wk = &sW[k * 81];
  const float* cu = ws + WS_CU;
  float sAcc = 0.f, ssAcc = 0.f;
  for (int m = blockIdx.x; m < M; m += gridDim.x) {
    int r[5], c[5];
    const int2* xp = (const int2*)(x + m * 10);
#pragma unroll
    for (int cc = 0; cc < 5; ++cc) { int2 t = xp[cc]; r[cc] = t.x; c[cc] = t.y; }
    float a0[4];
#pragma unroll
    for (int xx = 0; xx < 4; ++xx) {
      float v = cb;
#pragma unroll
      for (int cc = 0; cc < 5; ++cc)
        v += Wk[conv_idx(r[cc] - y, c[cc] - xx, cc)];
      a0[xx] = fmaxf(al * v + be, 0.f);
    }
    __builtin_amdgcn_sched_barrier(0);
    float r1[32];
#pragma unroll
    for (int o = 0; o < 32; ++o) {
      float acc = b_rank[o] + zbg * cu[o];
#pragma unroll
      for (int xx = 0; xx < 4; ++xx) acc += a0[xx] * w_rank[o * 10 + xx];
      r1[o] = fmaxf(acc, 0.f);
    }
    __builtin_amdgcn_sched_barrier(0);
    float s1 = 0.f, ss1 = 0.f;
#pragma unroll
    for (int ch = 0; ch < 4; ++ch) {
#pragma unroll
      for (int u = 0; u < 8; ++u) {
        const int o = ch * 8 + u;
        float acc = b_h1[o];
#pragma unroll
        for (int i = 0; i < 32; ++i) acc += r1[i] * w_h1[o * 32 + i];
        s1 += acc;
        ss1 += acc * acc;
      }
      __builtin_amdgcn_sched_barrier(0);
    }
    sAcc += s1;
    ssAcc += ss1;
  }
  sAcc  += __shfl_xor(sAcc, 1);  sAcc  += __shfl_xor(sAcc, 2);
  ssAcc += __shfl_xor(ssAcc, 1); ssAcc += __shfl_xor(ssAcc, 2);
  if (y == 0) {
    atomicAdd(&ws[WS_SUM1 + k], sAcc);
    atomicAdd(&ws[WS_SSQ1 + k], ssAcc);
  }
}

__global__ __launch_bounds__(256) void k_stats2(
    const int* __restrict__ x, const float* __restrict__ conv_w,
    const float* __restrict__ conv_b, const float* __restrict__ w_rank,
    const float* __restrict__ b_rank, const float* __restrict__ w_h1,
    const float* __restrict__ b_h1, const float* __restrict__ w_h2,
    const float* __restrict__ b_h2, float* __restrict__ ws, int M) {
  __shared__ float sW[CONV_LDS];
  stage_conv(sW, conv_w, 256);
  __syncthreads();
  const int tid = threadIdx.x;
  const int y = tid & 3, k = tid >> 2;
  const float cb = conv_b[k];
  const float al = ws[WS_AL0 + k], be = ws[WS_BE0 + k], zbg = ws[WS_ZBG + k];
  const float al1 = ws[WS_AL1 + k], be1 = ws[WS_BE1 + k];
  const float* Wk = &sW[k * 81];
  const float* cu = ws + WS_CU;
  float sAcc = 0.f, ssAcc = 0.f;
  for (int m = blockIdx.x; m < M; m += gridDim.x) {
    int r[5], c[5];
    const int2* xp = (const int2*)(x + m * 10);
#pragma unroll
    for (int cc = 0; cc < 5; ++cc) { int2 t = xp[cc]; r[cc] = t.x; c[cc] = t.y; }
    float a0[4];
#pragma unroll
    for (int xx = 0; xx < 4; ++xx) {
      float v = cb;
#pragma unroll
      for (int cc = 0; cc < 5; ++cc)
        v += Wk[conv_idx(r[cc] - y, c[cc] - xx, cc)];
      a0[xx] = fmaxf(al * v + be, 0.f);
    }
    __builtin_amdgcn_sched_barrier(0);
    float r1[32];
#pragma unroll
    for (int o = 0; o < 32; ++o) {
      float acc = b_rank[o] + zbg * cu[o];
#pragma unroll
      for (int xx = 0; xx < 4; ++xx) acc += a0[xx] * w_rank[o * 10 + xx];
      r1[o] = fmaxf(acc, 0.f);
    }
    __builtin_amdgcn_sched_barrier(0);
    float t2[16];
#pragma unroll
    for (int p = 0; p < 16; ++p) t2[p] = b_h2[p];
#pragma unroll
    for (int ch = 0; ch < 4; ++ch) {
      float a1c[8];
#pragma unroll
      for (int u = 0; u < 8; ++u) {
        const int o = ch * 8 + u;
        float acc = b_h1[o];
#pragma unroll
        for (int i = 0; i < 32; ++i) acc += r1[i] * w_h1[o * 32 + i];
        a1c[u] = fmaxf(al1 * acc + be1, 0.f);
      }
      __builtin_amdgcn_sched_barrier(0);
#pragma unroll
      for (int p = 0; p < 16; ++p) {
        float acc = t2[p];
#pragma unroll
        for (int u = 0; u < 8; ++u) acc += a1c[u] * w_h2[p * 32 + ch * 8 + u];
        t2[p] = acc;
      }
      __builtin_amdgcn_sched_barrier(0);
    }
    float s2l = 0.f, ss2l = 0.f;
#pragma unroll
    for (int p = 0; p < 16; ++p) { s2l += t2[p]; ss2l += t2[p] * t2[p]; }
    sAcc += s2l;
    ssAcc += ss2l;
  }
  sAcc  += __shfl_xor(sAcc, 1);  sAcc  += __shfl_xor(sAcc, 2);
  ssAcc += __shfl_xor(ssAcc, 1); ssAcc += __shfl_xor(ssAcc, 2);
  if (y == 0) {
    atomicAdd(&ws[WS_SUM2 + k], sAcc);
    atomicAdd(&ws[WS_SSQ2 + k], ssAcc);
  }
}

__global__ __launch_bounds__(64) void k_fin2(
    const float* __restrict__ g2, const float* __restrict__ b2,
    const float* __restrict__ w_out, const float* __restrict__ b_out,
    float* __restrict__ ws, int M) {
  __shared__ float red[64 * 9];
  const int k = threadIdx.x;
  const float n2 = (float)M * 11.f * 16.f;
  const float S = ws[WS_SUM2 + k], SS = ws[WS_SSQ2 + k];
  const float mu = S / n2;
  const float var = SS / n2 - mu * mu;
  const float rstd = rsqrtf(var + EPSV);
  const float al = rstd * g2[k];
  const float be = b2[k] - mu * al;
  ws[WS_AL2 + k] = al;
  ws[WS_BE2 + k] = be;
  float a2bg[16];
#pragma unroll
  for (int p = 0; p < 16; ++p)
    a2bg[p] = fmaxf(al * ws[WS_T2BG + k * 16 + p] + be, 0.f);
  for (int j = 0; j < 9; ++j) {
    float acc = 0.f;
#pragma unroll
    for (int p = 0; p < 16; ++p) {
      float wsum = 0.f;
#pragma unroll
      for (int yy = 4; yy < 11; ++yy)
        wsum += w_out[j * 11264 + k * 176 + yy * 16 + p];
      acc += a2bg[p] * wsum;
    }
    red[k * 9 + j] = acc;
  }
  __syncthreads();
  if (k < 9) {
    float acc = b_out[k];
    for (int t = 0; t < 64; ++t) acc += red[t * 9 + k];
    ws[WS_OC + k] = acc;
  }
}

__global__ __launch_bounds__(256) void k_final(
    const int* __restrict__ x, const float* __restrict__ conv_w,
    const float* __restrict__ conv_b, const float* __restrict__ w_rank,
    const float* __restrict__ b_rank, const float* __restrict__ w_h1,
    const float* __restrict__ b_h1, const float* __restrict__ w_h2,
    const float* __restrict__ b_h2, const float* __restrict__ w_out,
    const float* __restrict__ ws, float* __restrict__ out, int M) {
  __shared__ float sW[CONV_LDS];
  __shared__ float sOC[9];
  __shared__ float sRed[4][9];
  stage_conv(sW, conv_w, 256);
  if (threadIdx.x < 9) sOC[threadIdx.x] = ws[WS_OC + threadIdx.x];
  __syncthreads();
  const int tid = threadIdx.x;
  const int lane = tid & 63, wv = tid >> 6;
  const int y = tid & 3, k = tid >> 2;
  const float cb = conv_b[k];
  const float al = ws[WS_AL0 + k], be = ws[WS_BE0 + k], zbg = ws[WS_ZBG + k];
  const float al1 = ws[WS_AL1 + k], be1 = ws[WS_BE1 + k];
  const float al2 = ws[WS_AL2 + k], be2 = ws[WS_BE2 + k];
  const float* Wk = &sW[k * 81];
  const float* cu = ws + WS_CU;
  const float4* wo = (const float4*)(w_out + k * 176 + y * 16);
  bool first = true;
  for (int m = blockIdx.x; m < M; m += gridDim.x) {
    if (!first) __syncthreads();
    first = false;
    int r[5], c[5];
    const int2* xp = (const int2*)(x + m * 10);
#pragma unroll
    for (int cc = 0; cc < 5; ++cc) { int2 t = xp[cc]; r[cc] = t.x; c[cc] = t.y; }
    float a0[4];
#pragma unroll
    for (int xx = 0; xx < 4; ++xx) {
      float v = cb;
#pragma unroll
      for (int cc = 0; cc < 5; ++cc)
        v += Wk[conv_idx(r[cc] - y, c[cc] - xx, cc)];
      a0[xx] = fmaxf(al * v + be, 0.f);
    }
    __builtin_amdgcn_sched_barrier(0);
    float r1[32];
#pragma unroll
    for (int o = 0; o < 32; ++o) {
      float acc = b_rank[o] + zbg * cu[o];
#pragma unroll
      for (int xx = 0; xx < 4; ++xx) acc += a0[xx] * w_rank[o * 10 + xx];
      r1[o] = fmaxf(acc, 0.f);
    }
    __builtin_amdgcn_sched_barrier(0);
    float t2[16];
#pragma unroll
    for (int p = 0; p < 16; ++p) t2[p] = b_h2[p];
#pragma unroll
    for (int ch = 0; ch < 4; ++ch) {
      float a1c[8];
#pragma unroll
      for (int u = 0; u < 8; ++u) {
        const int o = ch * 8 + u;
        float acc = b_h1[o];
#pragma unroll
        for (int i = 0; i < 32; ++i) acc += r1[i] * w_h1[o * 32 + i];
        a1c[u] = fmaxf(al1 * acc + be1, 0.f);
      }
      __builtin_amdgcn_sched_barrier(0);
#pragma unroll
      for (int p = 0; p < 16; ++p) {
        float acc = t2[p];
#pragma unroll
        for (int u = 0; u < 8; ++u) acc += a1c[u] * w_h2[p * 32 + ch * 8 + u];
        t2[p] = acc;
      }
      __builtin_amdgcn_sched_barrier(0);
    }
    float a2[16];
#pragma unroll
    for (int p = 0; p < 16; ++p) a2[p] = fmaxf(al2 * t2[p] + be2, 0.f);
    float po[9];
#pragma unroll
    for (int j = 0; j < 9; ++j) {
      float4 w0 = wo[j * 2816 + 0], w1 = wo[j * 2816 + 1];
      float4 w2 = wo[j * 2816 + 2], w3 = wo[j * 2816 + 3];
      po[j] = a2[0] * w0.x + a2[1] * w0.y + a2[2] * w0.z + a2[3] * w0.w
            + a2[4] * w1.x + a2[5] * w1.y + a2[6] * w1.z + a2[7] * w1.w
            + a2[8] * w2.x + a2[9] * w2.y + a2[10] * w2.z + a2[11] * w2.w
            + a2[12] * w3.x + a2[13] * w3.y + a2[14] * w3.z + a2[15] * w3.w;
    }
#pragma unroll
    for (int j = 0; j < 9; ++j) {
      float v = po[j];
      v += __shfl_xor(v, 1);
      v += __shfl_xor(v, 2);
      v += __shfl_xor(v, 4);
      v += __shfl_xor(v, 8);
      v += __shfl_xor(v, 16);
      v += __shfl_xor(v, 32);
      po[j] = v;
    }
    if (lane == 0) {
#pragma unroll
      for (int j = 0; j < 9; ++j) sRed[wv][j] = po[j];
    }
    __syncthreads();
    if (tid < 9) {
      float acc = sOC[tid];
#pragma unroll
      for (int w2i = 0; w2i < 4; ++w2i) acc += sRed[w2i][tid];
      out[m * 9 + tid] = acc;
    }
  }
}

// ---------------------------------------------------------------------------
extern "C" void kernel_launch(void* const* d_in, const int* in_sizes, int n_in,
                              void* d_out, int out_size, void* d_ws, size_t ws_size,
                              hipStream_t stream) {
  const int*   x      = (const int*)d_in[0];
  const float* conv_w = (const float*)d_in[1];
  const float* conv_b = (const float*)d_in[2];
  const float* bn0_g  = (const float*)d_in[3];
  const float* bn0_b  = (const float*)d_in[4];
  const float* w_rank = (const float*)d_in[5];
  const float* b_rank = (const float*)d_in[6];
  const float* w_h1   = (const float*)d_in[7];
  const float* b_h1   = (const float*)d_in[8];
  const float* bn1_g  = (const float*)d_in[9];
  const float* bn1_b  = (const float*)d_in[10];
  const float* w_h2   = (const float*)d_in[11];
  const float* b_h2   = (const float*)d_in[12];
  const float* bn2_g  = (const float*)d_in[13];
  const float* bn2_b  = (const float*)d_in[14];
  const float* w_out  = (const float*)d_in[15];
  const float* b_out  = (const float*)d_in[16];
  float* out = (float*)d_out;
  float* ws  = (float*)d_ws;
  const int M = in_sizes[0] / 10;
  const size_t need = ((size_t)WS_T1 + (size_t)M * 4096) * sizeof(float);
  const int NP = (M + 1) >> 1;
  const int gridt = NP < 256 ? NP : 256;     // 8 pairs/block (curve bracket test)
  const int grid2 = NP < 512 ? NP : 512;

  if (ws_size >= need) {
    float* t1 = ws + WS_T1;
    k_prep3<<<60, 256, 0, stream>>>(x, conv_w, w_out, ws, M);
    k_stats0h<<<64, 256, 0, stream>>>(conv_b, ws, M);
    k_t1<<<gridt, 256, 0, stream>>>(x, conv_b, bn0_g, bn0_b, w_rank, b_rank,
                                    w_h1, b_h1, ws, t1, M);
    k_t2<<<grid2, 256, 0, stream>>>(conv_b, bn0_g, bn0_b, w_rank, b_rank,
                                    w_h1, b_h1, bn1_g, bn1_b, w_h2, b_h2,
                                    ws, t1, M);
    k_fin2p<<<1, 256, 0, stream>>>(conv_b, bn0_g, bn0_b, w_rank, b_rank,
                                   w_h1, b_h1, bn1_g, bn1_b, w_h2, b_h2,
                                   bn2_g, bn2_b, b_out, ws, M);
    k_out<<<grid2, 256, 0, stream>>>(w_out, ws, t1, out, M);
  } else {
    hipMemsetAsync(ws, 0, 384 * sizeof(float), stream);
    k_stats0<<<512, 256, 0, stream>>>(x, conv_w, conv_b, ws, M);
    k_fin0<<<1, 64, 0, stream>>>(conv_b, bn0_g, bn0_b, w_rank, b_rank, w_h1, b_h1, ws, M);
    k_stats1<<<1024, 256, 0, stream>>>(x, conv_w, conv_b, w_rank, b_rank, w_h1, b_h1,
                                       ws, M);
    k_fin1<<<1, 64, 0, stream>>>(bn1_g, bn1_b, w_h2, b_h2, ws, M);
    k_stats2<<<1024, 256, 0, stream>>>(x, conv_w, conv_b, w_rank, b_rank, w_h1, b_h1,
                                       w_h2, b_h2, ws, M);
    k_fin2<<<1, 64, 0, stream>>>(bn2_g, bn2_b, w_out, b_out, ws, M);
    k_final<<<1024, 256, 0, stream>>>(x, conv_w, conv_b, w_rank, b_rank, w_h1, b_h1,
                                      w_h2, b_h2, w_out, ws, out, M);
  }
}

// Round 15
// 252.493 us; speedup vs baseline: 1.1048x; 1.1048x over previous
//
#include <hip/hip_runtime.h>
#include <hip/hip_bf16.h>

#define EPSV 1e-5f

typedef float vf2 __attribute__((ext_vector_type(2)));
typedef _Float16 h4f __attribute__((ext_vector_type(4)));
typedef _Float16 h8f __attribute__((ext_vector_type(8)));

// Packed dual-FP32 FMA/MUL (VOP3P).
__device__ __forceinline__ vf2 pk_fma(vf2 a, vf2 b, vf2 c) {
  vf2 d;
  asm("v_pk_fma_f32 %0, %1, %2, %3" : "=v"(d) : "v"(a), "v"(b), "v"(c));
  return d;
}
__device__ __forceinline__ vf2 pk_mul(vf2 a, vf2 b) {
  vf2 d;
  asm("v_pk_mul_f32 %0, %1, %2" : "=v"(d) : "v"(a), "v"(b));
  return d;
}

// LDS-only barrier: does NOT drain vmcnt.
__device__ __forceinline__ void lds_barrier() {
  asm volatile("s_waitcnt lgkmcnt(0)" ::: "memory");
  __builtin_amdgcn_s_barrier();
}

// convert one h8f (8 fp16) into 4 vf2 with BN+relu
#define CVT4(dst, base, v, al, be)                               \
  dst[base + 0].x = fmaxf(al * (float)v[0] + be, 0.f);           \
  dst[base + 0].y = fmaxf(al * (float)v[1] + be, 0.f);           \
  dst[base + 1].x = fmaxf(al * (float)v[2] + be, 0.f);           \
  dst[base + 1].y = fmaxf(al * (float)v[3] + be, 0.f);           \
  dst[base + 2].x = fmaxf(al * (float)v[4] + be, 0.f);           \
  dst[base + 2].y = fmaxf(al * (float)v[5] + be, 0.f);           \
  dst[base + 3].x = fmaxf(al * (float)v[6] + be, 0.f);           \
  dst[base + 3].y = fmaxf(al * (float)v[7] + be, 0.f);

// workspace float offsets
#define WS_SUM0   0
#define WS_SSQ0   64
#define WS_SUM1   128
#define WS_SSQ1   192
#define WS_SUM2   256
#define WS_SSQ2   320
#define WS_AL0    384
#define WS_BE0    448
#define WS_ZBG    512
#define WS_T1BG   576      // 64*32 (fallback)
#define WS_AL1    2624
#define WS_BE1    2688
#define WS_T2BG   2752     // 64*16 (fallback)
#define WS_AL2    3776
#define WS_BE2    3840
#define WS_A2BG   3904
#define WS_OC     4928     // 9 used
#define WS_CU     4992     // 32 (fallback)
#define WS_CW     5120     // 5184: pre-repacked conv table
#define WS_WSUM   10304    // 9216: wsum[j][k*16+p]
#define WS_HSL    19584    // 16 slices * 2640 = 42240 (private histograms)
#define WS_T1     65536    // t1 fp16; layout [m][4 chunks][256 tid] h8 (16B)

#define CONV_LDS 5184
#define NHIST 2640

// slow repack — fallback only
__device__ __forceinline__ void stage_conv(float* sW, const float* __restrict__ conv_w,
                                           int nthr) {
  for (int i = threadIdx.x; i < 8000; i += nthr) {
    int k = i / 125, rem = i - k * 125;
    int cc = rem / 25, r2 = rem - cc * 25;
    int di = r2 / 5, dj = r2 - di * 5;
    if (di < 4 && dj < 4) sW[k * 81 + cc * 16 + di * 4 + dj] = conv_w[i];
  }
  for (int k = threadIdx.x; k < 64; k += nthr) sW[k * 81 + 80] = 0.f;
}

__device__ __forceinline__ void stage_conv_fast(float* sW, const float* __restrict__ cw) {
  const float4* src = (const float4*)cw;
  float4* dst = (float4*)sW;
  for (int i = threadIdx.x; i < CONV_LDS / 4; i += 256) dst[i] = src[i];
}

__device__ __forceinline__ int conv_idx(int di, int dj, int cc) {
  int idx = cc * 16 + di * 4 + dj;
  return ((di | dj) >= 0) ? idx : 80;
}

// ---------------------------------------------------------------------------
// Kernel P: blocks 0-7 repack conv_w; 8-43 wsum; 44-59 private histograms.
__global__ __launch_bounds__(256) void k_prep3(
    const int* __restrict__ x, const float* __restrict__ conv_w,
    const float* __restrict__ w_out, float* __restrict__ ws, int M) {
  __shared__ float h[NHIST];
  const int b = blockIdx.x;
  const int tid = threadIdx.x;
  if (b < 8) {
    float* cw = ws + WS_CW;
    const int gid = b * 256 + tid;
    for (int i = gid; i < 8000; i += 8 * 256) {
      int k = i / 125, rem = i - k * 125;
      int cc = rem / 25, r2 = rem - cc * 25;
      int di = r2 / 5, dj = r2 - di * 5;
      if (di < 4 && dj < 4) cw[k * 81 + cc * 16 + di * 4 + dj] = conv_w[i];
    }
    for (int k = gid; k < 64; k += 8 * 256) cw[k * 81 + 80] = 0.f;
  } else if (b < 44) {
    const int gid = (b - 8) * 256 + tid;
    if (gid < 9216) {
      int j = gid / 1024, kp = gid - j * 1024;
      int k = kp >> 4, p = kp & 15;
      float s = 0.f;
#pragma unroll
      for (int yy = 4; yy < 11; ++yy)
        s += w_out[j * 11264 + k * 176 + yy * 16 + p];
      ws[WS_WSUM + gid] = s;
    }
  } else {
    const int slice = b - 44;
    for (int i = tid; i < NHIST; i += 256) h[i] = 0.f;
    __syncthreads();
    for (int m = slice * 256 + tid; m < M; m += 16 * 256) {
      int v[5];
      const int2* xp = (const int2*)(x + m * 10);
#pragma unroll
      for (int cc = 0; cc < 5; ++cc) {
        int2 t = xp[cc];
        v[cc] = (t.x << 2) | t.y;
      }
#pragma unroll
      for (int cc = 0; cc < 5; ++cc) atomicAdd(&h[cc * 16 + v[cc]], 1.f);
      int pr = 0;
#pragma unroll
      for (int a = 0; a < 5; ++a)
#pragma unroll
        for (int bb = a + 1; bb < 5; ++bb) {
          atomicAdd(&h[80 + pr * 256 + v[a] * 16 + v[bb]], 1.f);
          ++pr;
        }
    }
    __syncthreads();
    for (int i = tid; i < NHIST; i += 256)
      ws[WS_HSL + slice * NHIST + i] = h[i];
  }
}

// ---------------------------------------------------------------------------
// Kernel S: BN0 stats from private histogram slices. One block per channel k.
__global__ __launch_bounds__(256) void k_stats0h(
    const float* __restrict__ conv_b, float* __restrict__ ws, int M) {
  __shared__ float sWk[81];
  __shared__ float sH[NHIST];
  __shared__ float sRed[8];
  const int tid = threadIdx.x;
  const int k = blockIdx.x;
  if (tid < 81) sWk[tid] = ws[WS_CW + k * 81 + tid];
  for (int i = tid; i < NHIST; i += 256) {
    float s = 0.f;
#pragma unroll
    for (int sl = 0; sl < 16; ++sl) s += ws[WS_HSL + sl * NHIST + i];
    sH[i] = s;
  }
  __syncthreads();
  const float cb = conv_b[k];
  float L = 0.f, Q = 0.f, P = 0.f;
  for (int it = tid; it < 1280; it += 256) {
    int pos = it / 80, rem = it - pos * 80;
    int cc = rem >> 4, v = rem & 15;
    int y = pos >> 2, xx = pos & 3;
    float w = sWk[conv_idx((v >> 2) - y, (v & 3) - xx, cc)];
    float n = sH[cc * 16 + v];
    L += n * w;
    Q += n * w * w;
  }
  if (tid < 160) {
    int pos = tid / 10, pr = tid - pos * 10;
    int y = pos >> 2, xx = pos & 3;
    int a, b;
    if (pr < 4)      { a = 0; b = pr + 1; }
    else if (pr < 7) { a = 1; b = pr - 2; }
    else if (pr < 9) { a = 2; b = pr - 4; }
    else             { a = 3; b = 4; }
    const float* Hp = sH + 80 + pr * 256;
    for (int v1 = 0; v1 < 16; ++v1) {
      float w1 = sWk[conv_idx((v1 >> 2) - y, (v1 & 3) - xx, a)];
      float acc = 0.f;
#pragma unroll
      for (int v2 = 0; v2 < 16; ++v2) {
        float w2 = sWk[conv_idx((v2 >> 2) - y, (v2 & 3) - xx, b)];
        acc += Hp[v1 * 16 + v2] * w2;
      }
      P += w1 * acc;
    }
  }
  float A = L, B = Q + 2.f * cb * L + 2.f * P;
  A += __shfl_xor(A, 1);  B += __shfl_xor(B, 1);
  A += __shfl_xor(A, 2);  B += __shfl_xor(B, 2);
  A += __shfl_xor(A, 4);  B += __shfl_xor(B, 4);
  A += __shfl_xor(A, 8);  B += __shfl_xor(B, 8);
  A += __shfl_xor(A, 16); B += __shfl_xor(B, 16);
  A += __shfl_xor(A, 32); B += __shfl_xor(B, 32);
  const int lane = tid & 63, wv = tid >> 6;
  if (lane == 0) { sRed[wv * 2] = A; sRed[wv * 2 + 1] = B; }
  __syncthreads();
  if (tid == 0) {
    float At = sRed[0] + sRed[2] + sRed[4] + sRed[6];
    float Bt = sRed[1] + sRed[3] + sRed[5] + sRed[7];
    const float a16 = 16.f * (float)M;
    ws[WS_SUM0 + k] = At + a16 * cb;
    ws[WS_SSQ0 + k] = Bt + a16 * cb * cb;
    ws[WS_SUM1 + k] = 0.f;
    ws[WS_SSQ1 + k] = 0.f;
    ws[WS_SUM2 + k] = 0.f;
    ws[WS_SSQ2 + k] = 0.f;
  }
}

// ---------------------------------------------------------------------------
// Kernel 3 (converged config, grid 512): DUAL-m conv -> r1 -> h1(pk_fma,
// LDS fp32 weights) -> t1 (fp16 h8 stores); BN0 folded in; sched_barriers
// kept (register-pressure limiters). 4 pairs/block = measured optimum of
// staging-amortization vs TLP (2048:81.7, 1024:71.3, 512:64.4, 256:87.4 us).
__global__ __launch_bounds__(256) void k_t1(
    const int* __restrict__ x, const float* __restrict__ conv_b,
    const float* __restrict__ g0, const float* __restrict__ b0,
    const float* __restrict__ w_rank, const float* __restrict__ b_rank,
    const float* __restrict__ w_h1, const float* __restrict__ b_h1,
    float* __restrict__ ws, float* __restrict__ t1, int M) {
  __shared__ float sW[CONV_LDS];
  __shared__ float sWh1[1024];
  __shared__ float sCU[32];
  stage_conv_fast(sW, ws + WS_CW);
  {
    const float4* src = (const float4*)w_h1;
    float4* dst = (float4*)sWh1;
    if (threadIdx.x < 256) dst[threadIdx.x] = src[threadIdx.x];
  }
  if (threadIdx.x < 32) {
    float cuv = 0.f;
    for (int s2 = 4; s2 < 10; ++s2) cuv += w_rank[threadIdx.x * 10 + s2];
    sCU[threadIdx.x] = cuv;
  }
  __syncthreads();
  const int tid = threadIdx.x;
  const int y = tid & 3, k = tid >> 2;
  const float cb = conv_b[k];
  const float n0 = 110.f * (float)M;
  const float S0  = ws[WS_SUM0 + k] + 94.f * (float)M * cb;
  const float SS0 = ws[WS_SSQ0 + k] + 94.f * (float)M * cb * cb;
  const float mu0 = S0 / n0;
  const float var0 = SS0 / n0 - mu0 * mu0;
  const float al = rsqrtf(var0 + EPSV) * g0[k];
  const float be = b0[k] - mu0 * al;
  const float zbg = fmaxf(cb * al + be, 0.f);
  const float* Wk = &sW[k * 81];
  const vf2* wrp = (const vf2*)w_rank;
  const vf2* w1p = (const vf2*)sWh1;
  h8f* t1h8 = (h8f*)t1;
  float sAcc = 0.f, ssAcc = 0.f;
  const int NP = (M + 1) >> 1;
  for (int mp = blockIdx.x; mp < NP; mp += gridDim.x) {
    const int mA = mp * 2, mB = mA + 1;
    const bool hasB = (mB < M);
    const int mBs = hasB ? mB : mA;
    int rA[5], cA[5], rB[5], cBx[5];
    const int2* xpA = (const int2*)(x + mA * 10);
    const int2* xpB = (const int2*)(x + mBs * 10);
#pragma unroll
    for (int cc = 0; cc < 5; ++cc) {
      int2 tA = xpA[cc]; rA[cc] = tA.x; cA[cc] = tA.y;
      int2 tB = xpB[cc]; rB[cc] = tB.x; cBx[cc] = tB.y;
    }
    float a0A[4], a0B[4];
#pragma unroll
    for (int xx = 0; xx < 4; ++xx) {
      float vA = cb, vB = cb;
#pragma unroll
      for (int cc = 0; cc < 5; ++cc) {
        vA += Wk[conv_idx(rA[cc] - y, cA[cc] - xx, cc)];
        vB += Wk[conv_idx(rB[cc] - y, cBx[cc] - xx, cc)];
      }
      a0A[xx] = fmaxf(al * vA + be, 0.f);
      a0B[xx] = fmaxf(al * vB + be, 0.f);
    }
    vf2 aAp[2], aBp[2];
    aAp[0].x = a0A[0]; aAp[0].y = a0A[1];
    aAp[1].x = a0A[2]; aAp[1].y = a0A[3];
    aBp[0].x = a0B[0]; aBp[0].y = a0B[1];
    aBp[1].x = a0B[2]; aBp[1].y = a0B[3];
    __builtin_amdgcn_sched_barrier(0);
    vf2 r1A[16], r1B[16];
#pragma unroll
    for (int o2 = 0; o2 < 16; ++o2) {
      const int oa = 2 * o2, ob = oa + 1;
      vf2 w0 = wrp[oa * 5], w1 = wrp[oa * 5 + 1];
      vf2 w2 = wrp[ob * 5], w3 = wrp[ob * 5 + 1];
      const float basea = b_rank[oa] + zbg * sCU[oa];
      const float baseb = b_rank[ob] + zbg * sCU[ob];
      vf2 accAa = pk_mul(aAp[0], w0); accAa = pk_fma(aAp[1], w1, accAa);
      vf2 accAb = pk_mul(aAp[0], w2); accAb = pk_fma(aAp[1], w3, accAb);
      vf2 accBa = pk_mul(aBp[0], w0); accBa = pk_fma(aBp[1], w1, accBa);
      vf2 accBb = pk_mul(aBp[0], w2); accBb = pk_fma(aBp[1], w3, accBb);
      vf2 ra, rb;
      ra.x = fmaxf(basea + accAa.x + accAa.y, 0.f);
      ra.y = fmaxf(baseb + accAb.x + accAb.y, 0.f);
      rb.x = fmaxf(basea + accBa.x + accBa.y, 0.f);
      rb.y = fmaxf(baseb + accBb.x + accBb.y, 0.f);
      r1A[o2] = ra;
      r1B[o2] = rb;
    }
    __builtin_amdgcn_sched_barrier(0);
    float sBm = 0.f, ssBm = 0.f;
#pragma unroll
    for (int ch = 0; ch < 4; ++ch) {
      float accA[8], accB[8];
#pragma unroll
      for (int u = 0; u < 8; ++u) {
        const int o = ch * 8 + u;
        vf2 a2A = {0.f, 0.f}, a2B = {0.f, 0.f};
#pragma unroll
        for (int i = 0; i < 16; ++i) {
          vf2 w = w1p[o * 16 + i];
          a2A = pk_fma(r1A[i], w, a2A);
          a2B = pk_fma(r1B[i], w, a2B);
        }
        const float bb = b_h1[o];
        float aA = bb + a2A.x + a2A.y;
        float aB = bb + a2B.x + a2B.y;
        accA[u] = aA; accB[u] = aB;
        sAcc += aA; ssAcc += aA * aA;
        sBm += aB;  ssBm += aB * aB;
      }
      h8f stA;
#pragma unroll
      for (int u = 0; u < 8; ++u) stA[u] = (_Float16)accA[u];
      t1h8[((size_t)mA * 4 + ch) * 256 + tid] = stA;
      if (hasB) {
        h8f stB;
#pragma unroll
        for (int u = 0; u < 8; ++u) stB[u] = (_Float16)accB[u];
        t1h8[((size_t)mB * 4 + ch) * 256 + tid] = stB;
      }
      __builtin_amdgcn_sched_barrier(0);
    }
    if (hasB) { sAcc += sBm; ssAcc += ssBm; }
  }
  sAcc  += __shfl_xor(sAcc, 1);  sAcc  += __shfl_xor(sAcc, 2);
  ssAcc += __shfl_xor(ssAcc, 1); ssAcc += __shfl_xor(ssAcc, 2);
  if (y == 0) {
    atomicAdd(&ws[WS_SUM1 + k], sAcc);
    atomicAdd(&ws[WS_SSQ1 + k], ssAcc);
  }
}

// ---------------------------------------------------------------------------
// Kernel 5: BN1 finalize folded in; grid 512, 4 pairs/block, 2-deep prefetch.
__global__ __launch_bounds__(256) void k_t2(
    const float* __restrict__ conv_b, const float* __restrict__ g0,
    const float* __restrict__ b0, const float* __restrict__ w_rank,
    const float* __restrict__ b_rank, const float* __restrict__ w_h1,
    const float* __restrict__ b_h1, const float* __restrict__ g1,
    const float* __restrict__ b1, const float* __restrict__ w_h2,
    const float* __restrict__ b_h2, float* __restrict__ ws,
    float* __restrict__ t1, int M) {
  __shared__ float sS[32];
  __shared__ float sWh1[1024];
  const int tid = threadIdx.x;
  for (int i = tid; i < 1024; i += 256) sWh1[i] = w_h1[i];
  if (tid < 32) {
    float s = 0.f;
    for (int s2 = 0; s2 < 10; ++s2) s += w_rank[tid * 10 + s2];
    sS[tid] = s;
  }
  __syncthreads();
  const int y = tid & 3, k = tid >> 2;
  const float fM = (float)M;
  const float cb = conv_b[k];
  const float n0 = 110.f * fM;
  const float S0  = ws[WS_SUM0 + k] + 94.f * fM * cb;
  const float SS0 = ws[WS_SSQ0 + k] + 94.f * fM * cb * cb;
  const float mu0 = S0 / n0;
  const float al0 = rsqrtf(SS0 / n0 - mu0 * mu0 + EPSV) * g0[k];
  const float be0 = b0[k] - mu0 * al0;
  const float zbg = fmaxf(cb * al0 + be0, 0.f);
  float r1bg[32];
#pragma unroll
  for (int o = 0; o < 32; ++o) r1bg[o] = fmaxf(zbg * sS[o] + b_rank[o], 0.f);
  float sb = 0.f, ssb = 0.f;
#pragma unroll
  for (int u = 0; u < 8; ++u) {
    const int o = y * 8 + u;
    float a = b_h1[o];
#pragma unroll
    for (int i = 0; i < 32; ++i) a += r1bg[i] * sWh1[o * 32 + i];
    sb += a;
    ssb += a * a;
  }
  sb  += __shfl_xor(sb, 1);  sb  += __shfl_xor(sb, 2);
  ssb += __shfl_xor(ssb, 1); ssb += __shfl_xor(ssb, 2);
  const float n1 = fM * 11.f * 32.f;
  const float S1  = ws[WS_SUM1 + k] + 7.f * fM * sb;
  const float SS1 = ws[WS_SSQ1 + k] + 7.f * fM * ssb;
  const float mu1 = S1 / n1;
  const float al1 = rsqrtf(SS1 / n1 - mu1 * mu1 + EPSV) * g1[k];
  const float be1 = b1[k] - mu1 * al1;
  // main loop with prefetch pipeline
  const vf2* w2p = (const vf2*)w_h2;
  h8f* t1h8 = (h8f*)t1;
  float sAcc = 0.f, ssAcc = 0.f;
  const int NP = (M + 1) >> 1;
  const int G = gridDim.x;
  int mp = blockIdx.x;
  h8f cA0, cA1, cA2, cA3, cB0, cB1, cB2, cB3;
  h8f nA0, nA1, nA2, nA3, nB0, nB1, nB2, nB3;
  if (mp < NP) {
    const int mA = mp * 2;
    const int mBs = (mA + 1 < M) ? mA + 1 : mA;
    cA0 = t1h8[((size_t)mA * 4 + 0) * 256 + tid];
    cA1 = t1h8[((size_t)mA * 4 + 1) * 256 + tid];
    cA2 = t1h8[((size_t)mA * 4 + 2) * 256 + tid];
    cA3 = t1h8[((size_t)mA * 4 + 3) * 256 + tid];
    cB0 = t1h8[((size_t)mBs * 4 + 0) * 256 + tid];
    cB1 = t1h8[((size_t)mBs * 4 + 1) * 256 + tid];
    cB2 = t1h8[((size_t)mBs * 4 + 2) * 256 + tid];
    cB3 = t1h8[((size_t)mBs * 4 + 3) * 256 + tid];
  }
  while (mp < NP) {
    const int mA = mp * 2, mB = mA + 1;
    const bool hasB = (mB < M);
    const int mpn = mp + G;
    if (mpn < NP) {
      const int mAn = mpn * 2;
      const int mBn = (mAn + 1 < M) ? mAn + 1 : mAn;
      nA0 = t1h8[((size_t)mAn * 4 + 0) * 256 + tid];
      nA1 = t1h8[((size_t)mAn * 4 + 1) * 256 + tid];
      nA2 = t1h8[((size_t)mAn * 4 + 2) * 256 + tid];
      nA3 = t1h8[((size_t)mAn * 4 + 3) * 256 + tid];
      nB0 = t1h8[((size_t)mBn * 4 + 0) * 256 + tid];
      nB1 = t1h8[((size_t)mBn * 4 + 1) * 256 + tid];
      nB2 = t1h8[((size_t)mBn * 4 + 2) * 256 + tid];
      nB3 = t1h8[((size_t)mBn * 4 + 3) * 256 + tid];
    }
    vf2 a1A[16], a1B[16];
    CVT4(a1A, 0,  cA0, al1, be1);
    CVT4(a1A, 4,  cA1, al1, be1);
    CVT4(a1A, 8,  cA2, al1, be1);
    CVT4(a1A, 12, cA3, al1, be1);
    CVT4(a1B, 0,  cB0, al1, be1);
    CVT4(a1B, 4,  cB1, al1, be1);
    CVT4(a1B, 8,  cB2, al1, be1);
    CVT4(a1B, 12, cB3, al1, be1);
    float sBm = 0.f, ssBm = 0.f;
#pragma unroll
    for (int pv2 = 0; pv2 < 2; ++pv2) {
      float accA[8], accB[8];
#pragma unroll
      for (int u = 0; u < 8; ++u) {
        const int p = pv2 * 8 + u;
        vf2 a2A = {0.f, 0.f}, a2B = {0.f, 0.f};
#pragma unroll
        for (int i = 0; i < 16; ++i) {
          vf2 w = w2p[p * 16 + i];
          a2A = pk_fma(a1A[i], w, a2A);
          a2B = pk_fma(a1B[i], w, a2B);
        }
        const float bb = b_h2[p];
        float aA = bb + a2A.x + a2A.y;
        float aB = bb + a2B.x + a2B.y;
        accA[u] = aA; accB[u] = aB;
        sAcc += aA; ssAcc += aA * aA;
        sBm += aB;  ssBm += aB * aB;
      }
      h8f stA;
#pragma unroll
      for (int u = 0; u < 8; ++u) stA[u] = (_Float16)accA[u];
      t1h8[((size_t)mA * 4 + pv2) * 256 + tid] = stA;
      if (hasB) {
        h8f stB;
#pragma unroll
        for (int u = 0; u < 8; ++u) stB[u] = (_Float16)accB[u];
        t1h8[((size_t)mB * 4 + pv2) * 256 + tid] = stB;
      }
    }
    if (hasB) { sAcc += sBm; ssAcc += ssBm; }
    mp = mpn;
    if (mp < NP) {
      cA0 = nA0; cA1 = nA1; cA2 = nA2; cA3 = nA3;
      cB0 = nB0; cB1 = nB1; cB2 = nB2; cB3 = nB3;
    }
  }
  sAcc  += __shfl_xor(sAcc, 1);  sAcc  += __shfl_xor(sAcc, 2);
  ssAcc += __shfl_xor(ssAcc, 1); ssAcc += __shfl_xor(ssAcc, 2);
  if (y == 0) {
    atomicAdd(&ws[WS_SUM2 + k], sAcc);
    atomicAdd(&ws[WS_SSQ2 + k], ssAcc);
  }
}

// ---------------------------------------------------------------------------
// Kernel 6: one block; recomputes bg chain; finalizes BN2; OC via wsum.
__global__ __launch_bounds__(256) void k_fin2p(
    const float* __restrict__ conv_b, const float* __restrict__ g0,
    const float* __restrict__ b0, const float* __restrict__ w_rank,
    const float* __restrict__ b_rank, const float* __restrict__ w_h1,
    const float* __restrict__ b_h1, const float* __restrict__ g1,
    const float* __restrict__ b1, const float* __restrict__ w_h2,
    const float* __restrict__ b_h2, const float* __restrict__ g2,
    const float* __restrict__ b2, const float* __restrict__ b_out,
    float* __restrict__ ws, int M) {
  __shared__ float sS[32];
  __shared__ float sWh1[1024];
  __shared__ float sWh2[512];
  __shared__ float sWs[9216];
  __shared__ float sA2[1024];
  __shared__ float red[576];
  const int tid = threadIdx.x;
  for (int i = tid; i < 1024; i += 256) sWh1[i] = w_h1[i];
  for (int i = tid; i < 512; i += 256) sWh2[i] = w_h2[i];
  for (int i = tid; i < 9216; i += 256) sWs[i] = ws[WS_WSUM + i];
  if (tid < 32) {
    float s = 0.f;
    for (int s2 = 0; s2 < 10; ++s2) s += w_rank[tid * 10 + s2];
    sS[tid] = s;
  }
  __syncthreads();
  const int k = tid >> 2, q = tid & 3;
  const float fM = (float)M;
  const float cb = conv_b[k];
  const float n0 = 110.f * fM;
  const float S0  = ws[WS_SUM0 + k] + 94.f * fM * cb;
  const float SS0 = ws[WS_SSQ0 + k] + 94.f * fM * cb * cb;
  const float mu0 = S0 / n0;
  const float al0 = rsqrtf(SS0 / n0 - mu0 * mu0 + EPSV) * g0[k];
  const float be0 = b0[k] - mu0 * al0;
  const float zbg = fmaxf(cb * al0 + be0, 0.f);
  float r1bg[32];
#pragma unroll
  for (int o = 0; o < 32; ++o) r1bg[o] = fmaxf(zbg * sS[o] + b_rank[o], 0.f);
  float t1bg[8];
  float sb = 0.f, ssb = 0.f;
#pragma unroll
  for (int u = 0; u < 8; ++u) {
    const int o = q * 8 + u;
    float a = b_h1[o];
#pragma unroll
    for (int i = 0; i < 32; ++i) a += r1bg[i] * sWh1[o * 32 + i];
    t1bg[u] = a;
    sb += a;
    ssb += a * a;
  }
  sb  += __shfl_xor(sb, 1);  sb  += __shfl_xor(sb, 2);
  ssb += __shfl_xor(ssb, 1); ssb += __shfl_xor(ssb, 2);
  const float n1 = fM * 11.f * 32.f;
  const float S1  = ws[WS_SUM1 + k] + 7.f * fM * sb;
  const float SS1 = ws[WS_SSQ1 + k] + 7.f * fM * ssb;
  const float mu1 = S1 / n1;
  const float al1 = rsqrtf(SS1 / n1 - mu1 * mu1 + EPSV) * g1[k];
  const float be1 = b1[k] - mu1 * al1;
  float a1bg[8];
#pragma unroll
  for (int u = 0; u < 8; ++u) a1bg[u] = fmaxf(al1 * t1bg[u] + be1, 0.f);
  float pt[16];
#pragma unroll
  for (int p = 0; p < 16; ++p) {
    float a = 0.f;
#pragma unroll
    for (int u = 0; u < 8; ++u) a += a1bg[u] * sWh2[p * 32 + q * 8 + u];
    pt[p] = a;
  }
#pragma unroll
  for (int p = 0; p < 16; ++p) {
    pt[p] += __shfl_xor(pt[p], 1);
    pt[p] += __shfl_xor(pt[p], 2);
  }
  float sb2 = 0.f, ssb2 = 0.f;
#pragma unroll
  for (int p = 0; p < 16; ++p) {
    float v = pt[p] + b_h2[p];
    pt[p] = v;
    sb2 += v;
    ssb2 += v * v;
  }
  const float n2 = fM * 11.f * 16.f;
  const float S2  = ws[WS_SUM2 + k] + 7.f * fM * sb2;
  const float SS2 = ws[WS_SSQ2 + k] + 7.f * fM * ssb2;
  const float mu2 = S2 / n2;
  const float al2 = rsqrtf(SS2 / n2 - mu2 * mu2 + EPSV) * g2[k];
  const float be2 = b2[k] - mu2 * al2;
  if (q == 0) {
    ws[WS_AL2 + k] = al2;
    ws[WS_BE2 + k] = be2;
  }
#pragma unroll
  for (int v2 = 0; v2 < 4; ++v2) {
    const int p = q * 4 + v2;
    sA2[k * 16 + p] = fmaxf(al2 * pt[p] + be2, 0.f);
  }
  __syncthreads();
  for (int u = tid; u < 576; u += 256) {
    const int kk = u / 9, j = u - kk * 9;
    float acc = 0.f;
#pragma unroll
    for (int p = 0; p < 16; ++p)
      acc += sA2[kk * 16 + p] * sWs[j * 1024 + kk * 16 + p];
    red[u] = acc;
  }
  __syncthreads();
  if (tid < 9) {
    float acc = b_out[tid];
    for (int t = 0; t < 64; ++t) acc += red[t * 9 + tid];
    ws[WS_OC + tid] = acc;
  }
}

// ---------------------------------------------------------------------------
// Kernel 7: grid 512, prefetch pipeline; 16B t2 loads; LDS-only barriers.
__global__ __launch_bounds__(256) void k_out(
    const float* __restrict__ w_out, const float* __restrict__ ws,
    const float* __restrict__ t1, float* __restrict__ out, int M) {
  __shared__ float sOC[9];
  __shared__ float sP[256][19];
  __shared__ float sR2[18 * 8];
  if (threadIdx.x < 9) sOC[threadIdx.x] = ws[WS_OC + threadIdx.x];
  const int tid = threadIdx.x;
  const int y = tid & 3, k = tid >> 2;
  const float al2 = ws[WS_AL2 + k], be2 = ws[WS_BE2 + k];
  const float4* wo = (const float4*)(w_out + k * 176 + y * 16);
  const h8f* t2h8 = (const h8f*)t1;
  const int NP = (M + 1) >> 1;
  const int G = gridDim.x;
  int mp = blockIdx.x;
  h8f cA0, cA1, cB0, cB1, nA0, nA1, nB0, nB1;
  if (mp < NP) {
    const int mA = mp * 2;
    const int mBs = (mA + 1 < M) ? mA + 1 : mA;
    cA0 = t2h8[((size_t)mA * 4 + 0) * 256 + tid];
    cA1 = t2h8[((size_t)mA * 4 + 1) * 256 + tid];
    cB0 = t2h8[((size_t)mBs * 4 + 0) * 256 + tid];
    cB1 = t2h8[((size_t)mBs * 4 + 1) * 256 + tid];
  }
  bool first = true;
  while (mp < NP) {
    const int mA = mp * 2, mB = mA + 1;
    const bool hasB = (mB < M);
    const int mpn = mp + G;
    if (mpn < NP) {
      const int mAn = mpn * 2;
      const int mBn = (mAn + 1 < M) ? mAn + 1 : mAn;
      nA0 = t2h8[((size_t)mAn * 4 + 0) * 256 + tid];
      nA1 = t2h8[((size_t)mAn * 4 + 1) * 256 + tid];
      nB0 = t2h8[((size_t)mBn * 4 + 0) * 256 + tid];
      nB1 = t2h8[((size_t)mBn * 4 + 1) * 256 + tid];
    }
    vf2 a2A[8], a2B[8];
    CVT4(a2A, 0, cA0, al2, be2);
    CVT4(a2A, 4, cA1, al2, be2);
    CVT4(a2B, 0, cB0, al2, be2);
    CVT4(a2B, 4, cB1, al2, be2);
    if (!first) lds_barrier();
    first = false;
#pragma unroll
    for (int j = 0; j < 9; ++j) {
      float4 w0 = wo[j * 2816 + 0], w1 = wo[j * 2816 + 1];
      float4 w2 = wo[j * 2816 + 2], w3 = wo[j * 2816 + 3];
      vf2 aA = {0.f, 0.f}, aB = {0.f, 0.f};
      vf2 t;
      t.x = w0.x; t.y = w0.y; aA = pk_fma(a2A[0], t, aA); aB = pk_fma(a2B[0], t, aB);
      t.x = w0.z; t.y = w0.w; aA = pk_fma(a2A[1], t, aA); aB = pk_fma(a2B[1], t, aB);
      t.x = w1.x; t.y = w1.y; aA = pk_fma(a2A[2], t, aA); aB = pk_fma(a2B[2], t, aB);
      t.x = w1.z; t.y = w1.w; aA = pk_fma(a2A[3], t, aA); aB = pk_fma(a2B[3], t, aB);
      t.x = w2.x; t.y = w2.y; aA = pk_fma(a2A[4], t, aA); aB = pk_fma(a2B[4], t, aB);
      t.x = w2.z; t.y = w2.w; aA = pk_fma(a2A[5], t, aA); aB = pk_fma(a2B[5], t, aB);
      t.x = w3.x; t.y = w3.y; aA = pk_fma(a2A[6], t, aA); aB = pk_fma(a2B[6], t, aB);
      t.x = w3.z; t.y = w3.w; aA = pk_fma(a2A[7], t, aA); aB = pk_fma(a2B[7], t, aB);
      sP[tid][j] = aA.x + aA.y;
      sP[tid][9 + j] = aB.x + aB.y;
    }
    lds_barrier();
    if (tid < 144) {
      const int slot = tid / 8, part = tid & 7;
      float s = 0.f;
#pragma unroll 8
      for (int t = 0; t < 32; ++t) s += sP[part + t * 8][slot];
      sR2[slot * 8 + part] = s;
    }
    lds_barrier();
    if (tid < 18) {
      float s = 0.f;
#pragma unroll
      for (int p8 = 0; p8 < 8; ++p8) s += sR2[tid * 8 + p8];
      if (tid < 9) out[mA * 9 + tid] = sOC[tid] + s;
      else if (hasB) out[mB * 9 + (tid - 9)] = sOC[tid - 9] + s;
    }
    mp = mpn;
    if (mp < NP) {
      cA0 = nA0; cA1 = nA1; cB0 = nB0; cB1 = nB1;
    }
  }
}

// ===========================================================================
// FALLBACK PATH (ws too small): self-contained recompute kernels.
// ===========================================================================
__global__ __launch_bounds__(64) void k_fin0(
    const float* __restrict__ conv_b, const float* __restrict__ g0,
    const float* __restrict__ b0, const float* __restrict__ w_rank,
    const float* __restrict__ b_rank, const float* __restrict__ w_h1,
    const float* __restrict__ b_h1, float* __restrict__ ws, int M) {
  __shared__ float sS[32];
  const int t = threadIdx.x;
  if (t < 32) {
    float su = 0.f;
    for (int s2 = 0; s2 < 10; ++s2) su += w_rank[t * 10 + s2];
    sS[t] = su;
    float cu = 0.f;
    for (int s2 = 4; s2 < 10; ++s2) cu += w_rank[t * 10 + s2];
    ws[WS_CU + t] = cu;
  }
  __syncthreads();
  const int k = t;
  const float n0 = 110.f * (float)M;
  const float cb = conv_b[k];
  const float S  = ws[WS_SUM0 + k] + 94.f * (float)M * cb;
  const float SS = ws[WS_SSQ0 + k] + 94.f * (float)M * cb * cb;
  const float mu = S / n0;
  const float var = SS / n0 - mu * mu;
  const float rstd = rsqrtf(var + EPSV);
  const float al = rstd * g0[k];
  const float be = b0[k] - mu * al;
  ws[WS_AL0 + k] = al;
  ws[WS_BE0 + k] = be;
  const float zbg = fmaxf(cb * al + be, 0.f);
  ws[WS_ZBG + k] = zbg;
  float r1bg[32];
#pragma unroll
  for (int o = 0; o < 32; ++o) r1bg[o] = fmaxf(zbg * sS[o] + b_rank[o], 0.f);
  float sb = 0.f, ssb = 0.f;
  for (int o = 0; o < 32; ++o) {
    float acc = b_h1[o];
#pragma unroll
    for (int i = 0; i < 32; ++i) acc += r1bg[i] * w_h1[o * 32 + i];
    ws[WS_T1BG + k * 32 + o] = acc;
    sb += acc;
    ssb += acc * acc;
  }
  ws[WS_SUM1 + k] = 7.f * (float)M * sb;
  ws[WS_SSQ1 + k] = 7.f * (float)M * ssb;
}

__global__ __launch_bounds__(64) void k_fin1(
    const float* __restrict__ g1, const float* __restrict__ b1,
    const float* __restrict__ w_h2, const float* __restrict__ b_h2,
    float* __restrict__ ws, int M) {
  const int k = threadIdx.x;
  const float n1 = (float)M * 11.f * 32.f;
  const float S = ws[WS_SUM1 + k], SS = ws[WS_SSQ1 + k];
  const float mu = S / n1;
  const float var = SS / n1 - mu * mu;
  const float rstd = rsqrtf(var + EPSV);
  const float al = rstd * g1[k];
  const float be = b1[k] - mu * al;
  ws[WS_AL1 + k] = al;
  ws[WS_BE1 + k] = be;
  float a1bg[32];
#pragma unroll
  for (int o = 0; o < 32; ++o)
    a1bg[o] = fmaxf(al * ws[WS_T1BG + k * 32 + o] + be, 0.f);
  float sb = 0.f, ssb = 0.f;
  for (int p = 0; p < 16; ++p) {
    float acc = b_h2[p];
#pragma unroll
    for (int o = 0; o < 32; ++o) acc += a1bg[o] * w_h2[p * 32 + o];
    ws[WS_T2BG + k * 16 + p] = acc;
    sb += acc;
    ssb += acc * acc;
  }
  ws[WS_SUM2 + k] = 7.f * (float)M * sb;
  ws[WS_SSQ2 + k] = 7.f * (float)M * ssb;
}

__global__ __launch_bounds__(256) void k_stats0(
    const int* __restrict__ x, const float* __restrict__ conv_w,
    const float* __restrict__ conv_b, float* __restrict__ ws, int M) {
  __shared__ float sW[CONV_LDS];
  stage_conv(sW, conv_w, 256);
  __syncthreads();
  const int tid = threadIdx.x;
  const int mg = tid & 3;
  const int k  = tid >> 2;
  const float cb = conv_b[k];
  const float* Wk = &sW[k * 81];
  float s = 0.f, ss = 0.f;
  for (int m = blockIdx.x * 4 + mg; m < M; m += gridDim.x * 4) {
    int r[5], c[5];
    const int2* xp = (const int2*)(x + m * 10);
#pragma unroll
    for (int cc = 0; cc < 5; ++cc) { int2 t = xp[cc]; r[cc] = t.x; c[cc] = t.y; }
#pragma unroll
    for (int y = 0; y < 4; ++y) {
#pragma unroll
      for (int xx = 0; xx < 4; ++xx) {
        float v = cb;
#pragma unroll
        for (int cc = 0; cc < 5; ++cc)
          v += Wk[conv_idx(r[cc] - y, c[cc] - xx, cc)];
        s += v;
        ss += v * v;
      }
      __builtin_amdgcn_sched_barrier(0);
    }
  }
  s  += __shfl_xor(s, 1);  s  += __shfl_xor(s, 2);
  ss += __shfl_xor(ss, 1); ss += __shfl_xor(ss, 2);
  if (mg == 0) {
    atomicAdd(&ws[WS_SUM0 + k], s);
    atomicAdd(&ws[WS_SSQ0 + k], ss);
  }
}

__global__ __launch_bounds__(256) void k_stats1(
    const int* __restrict__ x, const float* __restrict__ conv_w,
    const float* __restrict__ conv_b, const float* __restrict__ w_rank,
    const float* __restrict__ b_rank, const float* __restrict__ w_h1,
    const float* __restrict__ b_h1, float* __restrict__ ws, int M) {
  __shared__ float sW[CONV_LDS];
  stage_conv(sW, conv_w, 256);
  __syncthreads();
  const int tid = threadIdx.x;
  const int y = tid & 3, k = tid >> 2;
  const float cb = conv_b[k];
  const float al = ws[WS_AL0 + k], be = ws[WS_BE0 + k], zbg = ws[WS_ZBG + k];
  const float* Wk = &sW[k * 81];
  const float* cu = ws + WS_CU;
  float sAcc = 0.f, ssAcc = 0.f;
  for (int m = blockIdx.x; m < M; m += gridDim.x) {
    int r[5], c[5];
    const int2* xp = (const int2*)(x + m * 10);
#pragma unroll
    for (int cc = 0; cc < 5; ++cc) { int2 t = xp[cc]; r[cc] = t.x; c[cc] = t.y; }
    float a0[4];
#pragma unroll
    for (int xx = 0; xx < 4; ++xx) {
      float v = cb;
#pragma unroll
      for (int cc = 0; cc < 5; ++cc)
        v += Wk[conv_idx(r[cc] - y, c[cc] - xx, cc)];
      a0[xx] = fmaxf(al * v + be, 0.f);
    }
    __builtin_amdgcn_sched_barrier(0);
    float r1[32];
#pragma unroll
    for (int o = 0; o < 32; ++o) {
      float acc = b_rank[o] + zbg * cu[o];
#pragma unroll
      for (int xx = 0; xx < 4; ++xx) acc += a0[xx] * w_rank[o * 10 + xx];
      r1[o] = fmaxf(acc, 0.f);
    }
    __builtin_amdgcn_sched_barrier(0);
    float s1 = 0.f, ss1 = 0.f;
#pragma unroll
    for (int ch = 0; ch < 4; ++ch) {
#pragma unroll
      for (int u = 0; u < 8; ++u) {
        const int o = ch * 8 + u;
        float acc = b_h1[o];
#pragma unroll
        for (int i = 0; i < 32; ++i) acc += r1[i] * w_h1[o * 32 + i];
        s1 += acc;
        ss1 += acc * acc;
      }
      __builtin_amdgcn_sched_barrier(0);
    }
    sAcc += s1;
    ssAcc += ss1;
  }
  sAcc  += __shfl_xor(sAcc, 1);  sAcc  += __shfl_xor(sAcc, 2);
  ssAcc += __shfl_xor(ssAcc, 1); ssAcc += __shfl_xor(ssAcc, 2);
  if (y == 0) {
    atomicAdd(&ws[WS_SUM1 + k], sAcc);
    atomicAdd(&ws[WS_SSQ1 + k], ssAcc);
  }
}

__global__ __launch_bounds__(256) void k_stats2(
    const int* __restrict__ x, const float* __restrict__ conv_w,
    const float* __restrict__ conv_b, const float* __restrict__ w_rank,
    const float* __restrict__ b_rank, const float* __restrict__ w_h1,
    const float* __restrict__ b_h1, const float* __restrict__ w_h2,
    const float* __restrict__ b_h2, float* __restrict__ ws, int M) {
  __shared__ float sW[CONV_LDS];
  stage_conv(sW, conv_w, 256);
  __syncthreads();
  const int tid = threadIdx.x;
  const int y = tid & 3, k = tid >> 2;
  const float cb = conv_b[k];
  const float al = ws[WS_AL0 + k], be = ws[WS_BE0 + k], zbg = ws[WS_ZBG + k];
  const float al1 = ws[WS_AL1 + k], be1 = ws[WS_BE1 + k];
  const float* Wk = &sW[k * 81];
  const float* cu = ws + WS_CU;
  float sAcc = 0.f, ssAcc = 0.f;
  for (int m = blockIdx.x; m < M; m += gridDim.x) {
    int r[5], c[5];
    const int2* xp = (const int2*)(x + m * 10);
#pragma unroll
    for (int cc = 0; cc < 5; ++cc) { int2 t = xp[cc]; r[cc] = t.x; c[cc] = t.y; }
    float a0[4];
#pragma unroll
    for (int xx = 0; xx < 4; ++xx) {
      float v = cb;
#pragma unroll
      for (int cc = 0; cc < 5; ++cc)
        v += Wk[conv_idx(r[cc] - y, c[cc] - xx, cc)];
      a0[xx] = fmaxf(al * v + be, 0.f);
    }
    __builtin_amdgcn_sched_barrier(0);
    float r1[32];
#pragma unroll
    for (int o = 0; o < 32; ++o) {
      float acc = b_rank[o] + zbg * cu[o];
#pragma unroll
      for (int xx = 0; xx < 4; ++xx) acc += a0[xx] * w_rank[o * 10 + xx];
      r1[o] = fmaxf(acc, 0.f);
    }
    __builtin_amdgcn_sched_barrier(0);
    float t2[16];
#pragma unroll
    for (int p = 0; p < 16; ++p) t2[p] = b_h2[p];
#pragma unroll
    for (int ch = 0; ch < 4; ++ch) {
      float a1c[8];
#pragma unroll
      for (int u = 0; u < 8; ++u) {
        const int o = ch * 8 + u;
        float acc = b_h1[o];
#pragma unroll
        for (int i = 0; i < 32; ++i) acc += r1[i] * w_h1[o * 32 + i];
        a1c[u] = fmaxf(al1 * acc + be1, 0.f);
      }
      __builtin_amdgcn_sched_barrier(0);
#pragma unroll
      for (int p = 0; p < 16; ++p) {
        float acc = t2[p];
#pragma unroll
        for (int u = 0; u < 8; ++u) acc += a1c[u] * w_h2[p * 32 + ch * 8 + u];
        t2[p] = acc;
      }
      __builtin_amdgcn_sched_barrier(0);
    }
    float s2l = 0.f, ss2l = 0.f;
#pragma unroll
    for (int p = 0; p < 16; ++p) { s2l += t2[p]; ss2l += t2[p] * t2[p]; }
    sAcc += s2l;
    ssAcc += ss2l;
  }
  sAcc  += __shfl_xor(sAcc, 1);  sAcc  += __shfl_xor(sAcc, 2);
  ssAcc += __shfl_xor(ssAcc, 1); ssAcc += __shfl_xor(ssAcc, 2);
  if (y == 0) {
    atomicAdd(&ws[WS_SUM2 + k], sAcc);
    atomicAdd(&ws[WS_SSQ2 + k], ssAcc);
  }
}

__global__ __launch_bounds__(64) void k_fin2(
    const float* __restrict__ g2, const float* __restrict__ b2,
    const float* __restrict__ w_out, const float* __restrict__ b_out,
    float* __restrict__ ws, int M) {
  __shared__ float red[64 * 9];
  const int k = threadIdx.x;
  const float n2 = (float)M * 11.f * 16.f;
  const float S = ws[WS_SUM2 + k], SS = ws[WS_SSQ2 + k];
  const float mu = S / n2;
  const float var = SS / n2 - mu * mu;
  const float rstd = rsqrtf(var + EPSV);
  const float al = rstd * g2[k];
  const float be = b2[k] - mu * al;
  ws[WS_AL2 + k] = al;
  ws[WS_BE2 + k] = be;
  float a2bg[16];
#pragma unroll
  for (int p = 0; p < 16; ++p)
    a2bg[p] = fmaxf(al * ws[WS_T2BG + k * 16 + p] + be, 0.f);
  for (int j = 0; j < 9; ++j) {
    float acc = 0.f;
#pragma unroll
    for (int p = 0; p < 16; ++p) {
      float wsum = 0.f;
#pragma unroll
      for (int yy = 4; yy < 11; ++yy)
        wsum += w_out[j * 11264 + k * 176 + yy * 16 + p];
      acc += a2bg[p] * wsum;
    }
    red[k * 9 + j] = acc;
  }
  __syncthreads();
  if (k < 9) {
    float acc = b_out[k];
    for (int t = 0; t < 64; ++t) acc += red[t * 9 + k];
    ws[WS_OC + k] = acc;
  }
}

__global__ __launch_bounds__(256) void k_final(
    const int* __restrict__ x, const float* __restrict__ conv_w,
    const float* __restrict__ conv_b, const float* __restrict__ w_rank,
    const float* __restrict__ b_rank, const float* __restrict__ w_h1,
    const float* __restrict__ b_h1, const float* __restrict__ w_h2,
    const float* __restrict__ b_h2, const float* __restrict__ w_out,
    const float* __restrict__ ws, float* __restrict__ out, int M) {
  __shared__ float sW[CONV_LDS];
  __shared__ float sOC[9];
  __shared__ float sRed[4][9];
  stage_conv(sW, conv_w, 256);
  if (threadIdx.x < 9) sOC[threadIdx.x] = ws[WS_OC + threadIdx.x];
  __syncthreads();
  const int tid = threadIdx.x;
  const int lane = tid & 63, wv = tid >> 6;
  const int y = tid & 3, k = tid >> 2;
  const float cb = conv_b[k];
  const float al = ws[WS_AL0 + k], be = ws[WS_BE0 + k], zbg = ws[WS_ZBG + k];
  const float al1 = ws[WS_AL1 + k], be1 = ws[WS_BE1 + k];
  const float al2 = ws[WS_AL2 + k], be2 = ws[WS_BE2 + k];
  const float* Wk = &sW[k * 81];
  const float* cu = ws + WS_CU;
  const float4* wo = (const float4*)(w_out + k * 176 + y * 16);
  bool first = true;
  for (int m = blockIdx.x; m < M; m += gridDim.x) {
    if (!first) __syncthreads();
    first = false;
    int r[5], c[5];
    const int2* xp = (const int2*)(x + m * 10);
#pragma unroll
    for (int cc = 0; cc < 5; ++cc) { int2 t = xp[cc]; r[cc] = t.x; c[cc] = t.y; }
    float a0[4];
#pragma unroll
    for (int xx = 0; xx < 4; ++xx) {
      float v = cb;
#pragma unroll
      for (int cc = 0; cc < 5; ++cc)
        v += Wk[conv_idx(r[cc] - y, c[cc] - xx, cc)];
      a0[xx] = fmaxf(al * v + be, 0.f);
    }
    __builtin_amdgcn_sched_barrier(0);
    float r1[32];
#pragma unroll
    for (int o = 0; o < 32; ++o) {
      float acc = b_rank[o] + zbg * cu[o];
#pragma unroll
      for (int xx = 0; xx < 4; ++xx) acc += a0[xx] * w_rank[o * 10 + xx];
      r1[o] = fmaxf(acc, 0.f);
    }
    __builtin_amdgcn_sched_barrier(0);
    float t2[16];
#pragma unroll
    for (int p = 0; p < 16; ++p) t2[p] = b_h2[p];
#pragma unroll
    for (int ch = 0; ch < 4; ++ch) {
      float a1c[8];
#pragma unroll
      for (int u = 0; u < 8; ++u) {
        const int o = ch * 8 + u;
        float acc = b_h1[o];
#pragma unroll
        for (int i = 0; i < 32; ++i) acc += r1[i] * w_h1[o * 32 + i];
        a1c[u] = fmaxf(al1 * acc + be1, 0.f);
      }
      __builtin_amdgcn_sched_barrier(0);
#pragma unroll
      for (int p = 0; p < 16; ++p) {
        float acc = t2[p];
#pragma unroll
        for (int u = 0; u < 8; ++u) acc += a1c[u] * w_h2[p * 32 + ch * 8 + u];
        t2[p] = acc;
      }
      __builtin_amdgcn_sched_barrier(0);
    }
    float a2[16];
#pragma unroll
    for (int p = 0; p < 16; ++p) a2[p] = fmaxf(al2 * t2[p] + be2, 0.f);
    float po[9];
#pragma unroll
    for (int j = 0; j < 9; ++j) {
      float4 w0 = wo[j * 2816 + 0], w1 = wo[j * 2816 + 1];
      float4 w2 = wo[j * 2816 + 2], w3 = wo[j * 2816 + 3];
      po[j] = a2[0] * w0.x + a2[1] * w0.y + a2[2] * w0.z + a2[3] * w0.w
            + a2[4] * w1.x + a2[5] * w1.y + a2[6] * w1.z + a2[7] * w1.w
            + a2[8] * w2.x + a2[9] * w2.y + a2[10] * w2.z + a2[11] * w2.w
            + a2[12] * w3.x + a2[13] * w3.y + a2[14] * w3.z + a2[15] * w3.w;
    }
#pragma unroll
    for (int j = 0; j < 9; ++j) {
      float v = po[j];
      v += __shfl_xor(v, 1);
      v += __shfl_xor(v, 2);
      v += __shfl_xor(v, 4);
      v += __shfl_xor(v, 8);
      v += __shfl_xor(v, 16);
      v += __shfl_xor(v, 32);
      po[j] = v;
    }
    if (lane == 0) {
#pragma unroll
      for (int j = 0; j < 9; ++j) sRed[wv][j] = po[j];
    }
    __syncthreads();
    if (tid < 9) {
      float acc = sOC[tid];
#pragma unroll
      for (int w2i = 0; w2i < 4; ++w2i) acc += sRed[w2i][tid];
      out[m * 9 + tid] = acc;
    }
  }
}

// ---------------------------------------------------------------------------
extern "C" void kernel_launch(void* const* d_in, const int* in_sizes, int n_in,
                              void* d_out, int out_size, void* d_ws, size_t ws_size,
                              hipStream_t stream) {
  const int*   x      = (const int*)d_in[0];
  const float* conv_w = (const float*)d_in[1];
  const float* conv_b = (const float*)d_in[2];
  const float* bn0_g  = (const float*)d_in[3];
  const float* bn0_b  = (const float*)d_in[4];
  const float* w_rank = (const float*)d_in[5];
  const float* b_rank = (const float*)d_in[6];
  const float* w_h1   = (const float*)d_in[7];
  const float* b_h1   = (const float*)d_in[8];
  const float* bn1_g  = (const float*)d_in[9];
  const float* bn1_b  = (const float*)d_in[10];
  const float* w_h2   = (const float*)d_in[11];
  const float* b_h2   = (const float*)d_in[12];
  const float* bn2_g  = (const float*)d_in[13];
  const float* bn2_b  = (const float*)d_in[14];
  const float* w_out  = (const float*)d_in[15];
  const float* b_out  = (const float*)d_in[16];
  float* out = (float*)d_out;
  float* ws  = (float*)d_ws;
  const int M = in_sizes[0] / 10;
  const size_t need = ((size_t)WS_T1 + (size_t)M * 4096) * sizeof(float);
  const int NP = (M + 1) >> 1;
  const int gridt = NP < 512 ? NP : 512;     // 4 pairs/block: measured optimum
  const int grid2 = NP < 512 ? NP : 512;

  if (ws_size >= need) {
    float* t1 = ws + WS_T1;
    k_prep3<<<60, 256, 0, stream>>>(x, conv_w, w_out, ws, M);
    k_stats0h<<<64, 256, 0, stream>>>(conv_b, ws, M);
    k_t1<<<gridt, 256, 0, stream>>>(x, conv_b, bn0_g, bn0_b, w_rank, b_rank,
                                    w_h1, b_h1, ws, t1, M);
    k_t2<<<grid2, 256, 0, stream>>>(conv_b, bn0_g, bn0_b, w_rank, b_rank,
                                    w_h1, b_h1, bn1_g, bn1_b, w_h2, b_h2,
                                    ws, t1, M);
    k_fin2p<<<1, 256, 0, stream>>>(conv_b, bn0_g, bn0_b, w_rank, b_rank,
                                   w_h1, b_h1, bn1_g, bn1_b, w_h2, b_h2,
                                   bn2_g, bn2_b, b_out, ws, M);
    k_out<<<grid2, 256, 0, stream>>>(w_out, ws, t1, out, M);
  } else {
    hipMemsetAsync(ws, 0, 384 * sizeof(float), stream);
    k_stats0<<<512, 256, 0, stream>>>(x, conv_w, conv_b, ws, M);
    k_fin0<<<1, 64, 0, stream>>>(conv_b, bn0_g, bn0_b, w_rank, b_rank, w_h1, b_h1, ws, M);
    k_stats1<<<1024, 256, 0, stream>>>(x, conv_w, conv_b, w_rank, b_rank, w_h1, b_h1,
                                       ws, M);
    k_fin1<<<1, 64, 0, stream>>>(bn1_g, bn1_b, w_h2, b_h2, ws, M);
    k_stats2<<<1024, 256, 0, stream>>>(x, conv_w, conv_b, w_rank, b_rank, w_h1, b_h1,
                                       w_h2, b_h2, ws, M);
    k_fin2<<<1, 64, 0, stream>>>(bn2_g, bn2_b, w_out, b_out, ws, M);
    k_final<<<1024, 256, 0, stream>>>(x, conv_w, conv_b, w_rank, b_rank, w_h1, b_h1,
                                      w_h2, b_h2, w_out, ws, out, M);
  }
}